// Round 1
// baseline (5202.714 us; speedup 1.0000x reference)
//
#include <hip/hip_runtime.h>
#include <hip/hip_bf16.h>

#define T_ 16
#define B_ 8
#define CIN 768
#define D_ 256
#define K_ 64
#define HW 784
#define W_ 28

// ---------------- block reduce helper ----------------
__device__ __forceinline__ float block_reduce_sum_256(float v) {
    for (int off = 32; off > 0; off >>= 1) v += __shfl_down(v, off, 64);
    __shared__ float red[4];
    __shared__ float tot;
    int lane = threadIdx.x & 63, wid = threadIdx.x >> 6;
    if (lane == 0) red[wid] = v;
    __syncthreads();
    if (threadIdx.x == 0) {
        float s = red[0] + red[1] + red[2] + red[3];
        tot = s;
    }
    __syncthreads();
    return tot;
}

// ---------------- 1x1 conv as batched GEMM ----------------
// Out[bt][m][p] = sum_k W[m][k] * X[bt][k][p] + bias[m]
// grid (pt=13, mt=M/64, bt=128), block 256. BM=BN=64, KB=16.
__global__ __launch_bounds__(256) void conv1x1_gemm(
    const float* __restrict__ X, const float* __restrict__ Wm,
    const float* __restrict__ bias, float* __restrict__ Out, int Kdim)
{
    int pt = blockIdx.x, mt = blockIdx.y, bt = blockIdx.z;
    int M = gridDim.y << 6;
    int p0 = pt * 64, m0 = mt * 64;
    const float* Xb = X + (size_t)bt * Kdim * HW;
    float* Ob = Out + (size_t)bt * M * HW;

    __shared__ float As[16][68];   // As[ks][m]
    __shared__ float Bs[16][68];   // Bs[ks][p]
    int tx = threadIdx.x & 15, ty = threadIdx.x >> 4;

    float acc[4][4] = {{0.f}};

    for (int k0 = 0; k0 < Kdim; k0 += 16) {
#pragma unroll
        for (int it = 0; it < 4; ++it) {
            int e = threadIdx.x + it * 256;    // 0..1023
            int m = e >> 4, ks = e & 15;
            As[ks][m] = Wm[(size_t)(m0 + m) * Kdim + k0 + ks];
            int ks2 = e >> 6, pp = e & 63;
            int p = p0 + pp;
            Bs[ks2][pp] = (p < HW) ? Xb[(size_t)(k0 + ks2) * HW + p] : 0.f;
        }
        __syncthreads();
#pragma unroll
        for (int ks = 0; ks < 16; ++ks) {
            float4 a = *(const float4*)&As[ks][ty * 4];
            float4 bv = *(const float4*)&Bs[ks][tx * 4];
            float av[4] = {a.x, a.y, a.z, a.w};
            float bvv[4] = {bv.x, bv.y, bv.z, bv.w};
#pragma unroll
            for (int r = 0; r < 4; ++r)
#pragma unroll
                for (int s = 0; s < 4; ++s)
                    acc[r][s] = fmaf(av[r], bvv[s], acc[r][s]);
        }
        __syncthreads();
    }

    int p = p0 + tx * 4;
    if (p < HW) {
#pragma unroll
        for (int r = 0; r < 4; ++r) {
            int m = m0 + ty * 4 + r;
            float bb = bias[m];
            float4 o;
            o.x = acc[r][0] + bb; o.y = acc[r][1] + bb;
            o.z = acc[r][2] + bb; o.w = acc[r][3] + bb;
            *(float4*)&Ob[(size_t)m * HW + p] = o;
        }
    }
}

// ---------------- ConvGRU phase A: z,r convs + rh ----------------
// grid (rt=7, kg=8, b=8), block 128. Each block: 8 k-planes, rows rt*4..rt*4+3.
__global__ __launch_bounds__(128) void gru_zr(
    const float* __restrict__ hprev, const float* __restrict__ wxb,
    const float* __restrict__ Uz, const float* __restrict__ Ur,
    float* __restrict__ zbuf, float* __restrict__ rhbuf, int t)
{
    int rt = blockIdx.x, kg = blockIdx.y, b = blockIdx.z;
    int k0 = kg * 8, r0 = rt * 4;
    __shared__ float lh[64 * 6 * 28];     // [c][row(6)][col(28)]
    const float* hb = hprev + (size_t)b * K_ * HW;

    for (int e = threadIdx.x; e < 64 * 6 * 28; e += 128) {
        int c = e / 168; int rem = e - c * 168;
        int rr = rem / 28, col = rem - rr * 28;
        int gr = r0 - 1 + rr;
        lh[e] = (gr >= 0 && gr < 28) ? hb[(size_t)c * HW + gr * 28 + col] : 0.f;
    }
    __syncthreads();

    int tid = threadIdx.x;
    if (tid >= 112) return;
    int pr = tid / 28, pc = tid - pr * 28;

    float accz[8] = {0.f}, accr[8] = {0.f};
#pragma unroll 2
    for (int c = 0; c < 64; ++c) {
        const float* lb = &lh[c * 168 + pr * 28 + pc];
        const float* uz = &Uz[((size_t)k0 * 64 + c) * 9];
        const float* ur = &Ur[((size_t)k0 * 64 + c) * 9];
#pragma unroll
        for (int dy = 0; dy < 3; ++dy) {
#pragma unroll
            for (int dx = 0; dx < 3; ++dx) {
                int col = pc + dx - 1;
                float hv = (col >= 0 && col < 28) ? lb[dy * 28 + dx - 1] : 0.f;
                int tap = dy * 3 + dx;
#pragma unroll
                for (int kk = 0; kk < 8; ++kk) {
                    accz[kk] = fmaf(hv, uz[kk * 576 + tap], accz[kk]);
                    accr[kk] = fmaf(hv, ur[kk * 576 + tap], accr[kk]);
                }
            }
        }
    }

    int pidx = (r0 + pr) * 28 + pc;
    int btq = b * T_ + t;
#pragma unroll
    for (int kk = 0; kk < 8; ++kk) {
        int k = k0 + kk;
        float w = wxb[((size_t)btq * K_ + k) * HW + pidx];
        float z = 1.f / (1.f + __expf(-(w + accz[kk])));
        float r = 1.f / (1.f + __expf(-(w + accr[kk])));
        float hp = hb[(size_t)k * HW + pidx];
        size_t o = ((size_t)b * K_ + k) * HW + pidx;
        zbuf[o] = z;
        rhbuf[o] = r * hp;
    }
}

// ---------------- ConvGRU phase B: candidate conv + update ----------------
__global__ __launch_bounds__(128) void gru_h(
    const float* __restrict__ rh, const float* __restrict__ hprev,
    const float* __restrict__ wxb, const float* __restrict__ Uh,
    const float* __restrict__ zbuf, float* __restrict__ hout, int t)
{
    int rt = blockIdx.x, kg = blockIdx.y, b = blockIdx.z;
    int k0 = kg * 8, r0 = rt * 4;
    __shared__ float lh[64 * 6 * 28];
    const float* rb = rh + (size_t)b * K_ * HW;
    const float* hbp = hprev + (size_t)b * K_ * HW;

    for (int e = threadIdx.x; e < 64 * 6 * 28; e += 128) {
        int c = e / 168; int rem = e - c * 168;
        int rr = rem / 28, col = rem - rr * 28;
        int gr = r0 - 1 + rr;
        lh[e] = (gr >= 0 && gr < 28) ? rb[(size_t)c * HW + gr * 28 + col] : 0.f;
    }
    __syncthreads();

    int tid = threadIdx.x;
    if (tid >= 112) return;
    int pr = tid / 28, pc = tid - pr * 28;

    float acch[8] = {0.f};
#pragma unroll 2
    for (int c = 0; c < 64; ++c) {
        const float* lb = &lh[c * 168 + pr * 28 + pc];
        const float* uh = &Uh[((size_t)k0 * 64 + c) * 9];
#pragma unroll
        for (int dy = 0; dy < 3; ++dy) {
#pragma unroll
            for (int dx = 0; dx < 3; ++dx) {
                int col = pc + dx - 1;
                float hv = (col >= 0 && col < 28) ? lb[dy * 28 + dx - 1] : 0.f;
                int tap = dy * 3 + dx;
#pragma unroll
                for (int kk = 0; kk < 8; ++kk)
                    acch[kk] = fmaf(hv, uh[kk * 576 + tap], acch[kk]);
            }
        }
    }

    int pidx = (r0 + pr) * 28 + pc;
    int btq = b * T_ + t;
#pragma unroll
    for (int kk = 0; kk < 8; ++kk) {
        int k = k0 + kk;
        float w = wxb[((size_t)btq * K_ + k) * HW + pidx];
        float xv = w + acch[kk];
        float e2 = __expf(2.f * xv);
        float th = 1.f - 2.f / (e2 + 1.f);     // tanh
        size_t o = ((size_t)b * K_ + k) * HW + pidx;
        float z = zbuf[o];
        float hp = hbp[(size_t)k * HW + pidx];
        hout[o] = (1.f - z) * th + z * hp;
    }
}

// ---------------- softmax over k (in place on hs) ----------------
// hs layout [q=128][k=64][p=784], q = t*8+b. grid 128, block 256.
__global__ __launch_bounds__(256) void softmax_k(float* __restrict__ hs)
{
    int q = blockIdx.x;
    float* base = hs + (size_t)q * K_ * HW;
    for (int p = threadIdx.x; p < HW; p += 256) {
        float v[64];
        float m = -1e30f;
#pragma unroll
        for (int k = 0; k < 64; ++k) {
            v[k] = base[(size_t)k * HW + p];
            m = fmaxf(m, v[k]);
        }
        float s = 0.f;
#pragma unroll
        for (int k = 0; k < 64; ++k) {
            v[k] = __expf(v[k] - m);
            s += v[k];
        }
        float inv = 1.f / s;
#pragma unroll
        for (int k = 0; k < 64; ++k)
            base[(size_t)k * HW + p] = v[k] * inv;
    }
}

// ---------------- a_sum (summed over t and p) ----------------
// grid 512 (b*64+k), block 256.
__global__ __launch_bounds__(256) void asum_k(const float* __restrict__ hs,
                                              float* __restrict__ asum)
{
    int bid = blockIdx.x; int b = bid >> 6, k = bid & 63;
    float s = 0.f;
    for (int t = 0; t < T_; ++t) {
        const float* row = hs + (((size_t)t * B_ + b) * K_ + k) * HW;
        for (int p = threadIdx.x; p < HW; p += 256) s += row[p];
    }
    float tot = block_reduce_sum_256(s);
    if (threadIdx.x == 0) asum[bid] = tot;
}

// ---------------- VLAD: per-(b,t) outer-product GEMM ----------------
// vladt[bt][k][d] = sum_p assign[q][k][p] * xr[bt][d][p]
// grid (dt=4, t=16, b=8), block 256.
__global__ __launch_bounds__(256) void vlad_k(const float* __restrict__ assign,
    const float* __restrict__ xr, float* __restrict__ vladt)
{
    int dt = blockIdx.x, t = blockIdx.y, b = blockIdx.z;
    int q = t * B_ + b, bt = b * T_ + t, d0 = dt * 64;
    const float* ab = assign + (size_t)q * K_ * HW;
    const float* xb = xr + (size_t)bt * D_ * HW;
    __shared__ float As[16][68];   // [pp][k]
    __shared__ float Xs[16][68];   // [pp][d]
    int tx = threadIdx.x & 15, ty = threadIdx.x >> 4;
    float acc[4][4] = {{0.f}};

    for (int p0 = 0; p0 < HW; p0 += 16) {
#pragma unroll
        for (int it = 0; it < 4; ++it) {
            int e = threadIdx.x + it * 256;
            int row = e >> 4, pp = e & 15;
            As[pp][row] = ab[(size_t)row * HW + p0 + pp];
            Xs[pp][row] = xb[(size_t)(d0 + row) * HW + p0 + pp];
        }
        __syncthreads();
#pragma unroll
        for (int pp = 0; pp < 16; ++pp) {
            float4 a = *(const float4*)&As[pp][ty * 4];
            float4 xv = *(const float4*)&Xs[pp][tx * 4];
            float av[4] = {a.x, a.y, a.z, a.w};
            float xvv[4] = {xv.x, xv.y, xv.z, xv.w};
#pragma unroll
            for (int r = 0; r < 4; ++r)
#pragma unroll
                for (int s = 0; s < 4; ++s)
                    acc[r][s] = fmaf(av[r], xvv[s], acc[r][s]);
        }
        __syncthreads();
    }
#pragma unroll
    for (int r = 0; r < 4; ++r) {
        int k = ty * 4 + r;
        float4 o = {acc[r][0], acc[r][1], acc[r][2], acc[r][3]};
        *(float4*)&vladt[((size_t)bt * K_ + k) * D_ + d0 + tx * 4] = o;
    }
}

// ---------------- reduce over t, subtract a_sum*centers, intra-norm ----------------
// grid 512 (b*64+k), block 256 (d = tid).
__global__ __launch_bounds__(256) void norm1_k(const float* __restrict__ vladt,
    const float* __restrict__ asum, const float* __restrict__ centers,
    float* __restrict__ out)
{
    int bid = blockIdx.x; int b = bid >> 6, k = bid & 63; int d = threadIdx.x;
    float acc = 0.f;
#pragma unroll
    for (int t = 0; t < T_; ++t)
        acc += vladt[(((size_t)b * T_ + t) * K_ + k) * D_ + d];
    acc -= asum[bid] * centers[(size_t)k * D_ + d];
    float ss = block_reduce_sum_256(acc * acc);
    float n = fmaxf(sqrtf(ss), 1e-12f);
    out[((size_t)b * K_ + k) * D_ + d] = acc / n;
}

// ---------------- global L2 norm per b (in place on out) ----------------
__global__ __launch_bounds__(256) void norm2_k(float* __restrict__ out)
{
    int b = blockIdx.x;
    float* v = out + (size_t)b * (K_ * D_);
    float s = 0.f;
    for (int i = threadIdx.x; i < K_ * D_; i += 256) {
        float x = v[i];
        s = fmaf(x, x, s);
    }
    float tot = block_reduce_sum_256(s);
    float n = fmaxf(sqrtf(tot), 1e-12f);
    for (int i = threadIdx.x; i < K_ * D_; i += 256) v[i] = v[i] / n;
}

// ---------------- launch ----------------
extern "C" void kernel_launch(void* const* d_in, const int* in_sizes, int n_in,
                              void* d_out, int out_size, void* d_ws, size_t ws_size,
                              hipStream_t stream)
{
    const float* x       = (const float*)d_in[0];
    const float* redu_w  = (const float*)d_in[1];
    const float* redu_b  = (const float*)d_in[2];
    const float* share_w = (const float*)d_in[3];
    const float* share_b = (const float*)d_in[4];
    const float* Uz      = (const float*)d_in[5];
    const float* Ur      = (const float*)d_in[6];
    const float* Uh      = (const float*)d_in[7];
    const float* centers = (const float*)d_in[8];

    float* ws = (float*)d_ws;
    const size_t SZ_XR   = (size_t)128 * D_ * HW;       // 25,690,112
    const size_t SZ_WXB  = (size_t)128 * K_ * HW;       //  6,422,528
    const size_t SZ_HS   = (size_t)T_ * B_ * K_ * HW;   //  6,422,528
    const size_t SZ_PLANE= (size_t)B_ * K_ * HW;        //    401,408
    float* xr    = ws;
    float* wxb   = xr + SZ_XR;
    float* hs    = wxb + SZ_WXB;
    float* h0    = hs + SZ_HS;
    float* zbuf  = h0 + SZ_PLANE;
    float* rhbuf = zbuf + SZ_PLANE;
    float* asumb = rhbuf + SZ_PLANE;                    // 512 floats
    float* vladt = asumb + 512;                         // 128*64*256

    hipMemsetAsync(h0, 0, SZ_PLANE * sizeof(float), stream);

    // 1) channel reduction: xr = redu_w @ x + redu_b
    conv1x1_gemm<<<dim3(13, 4, 128), 256, 0, stream>>>(x, redu_w, redu_b, xr, CIN);
    // 2) assignment logits: wxb = share_w @ xr + share_b
    conv1x1_gemm<<<dim3(13, 1, 128), 256, 0, stream>>>(xr, share_w, share_b, wxb, D_);

    // 3) ConvGRU over 16 timesteps
    for (int t = 0; t < T_; ++t) {
        const float* hp = (t == 0) ? h0 : hs + (size_t)(t - 1) * SZ_PLANE;
        gru_zr<<<dim3(7, 8, 8), 128, 0, stream>>>(hp, wxb, Uz, Ur, zbuf, rhbuf, t);
        gru_h<<<dim3(7, 8, 8), 128, 0, stream>>>(rhbuf, hp, wxb, Uh, zbuf,
                                                 hs + (size_t)t * SZ_PLANE, t);
    }

    // 4) softmax over centers, a_sum
    softmax_k<<<128, 256, 0, stream>>>(hs);
    asum_k<<<512, 256, 0, stream>>>(hs, asumb);

    // 5) VLAD aggregation + norms
    vlad_k<<<dim3(4, 16, 8), 256, 0, stream>>>(hs, xr, vladt);
    norm1_k<<<512, 256, 0, stream>>>(vladt, asumb, centers, (float*)d_out);
    norm2_k<<<8, 256, 0, stream>>>((float*)d_out);
}

// Round 2
// 4220.530 us; speedup vs baseline: 1.2327x; 1.2327x over previous
//
#include <hip/hip_runtime.h>
#include <hip/hip_bf16.h>

#define T_ 16
#define B_ 8
#define CIN 768
#define D_ 256
#define K_ 64
#define HW 784
#define W_ 28

typedef short short8 __attribute__((ext_vector_type(8)));
typedef float floatx4 __attribute__((ext_vector_type(4)));

// ---------------- bf16 split helpers ----------------
__device__ __forceinline__ unsigned short f2bf(float x) {
    union { float f; unsigned u; } v; v.f = x;
    unsigned u = v.u;
    unsigned r = (u + 0x7fffu + ((u >> 16) & 1u)) >> 16;   // RNE
    return (unsigned short)r;
}
__device__ __forceinline__ float bf2f(unsigned short h) {
    union { unsigned u; float f; } v; v.u = ((unsigned)h) << 16; return v.f;
}

// ---------------- block reduce helper ----------------
__device__ __forceinline__ float block_reduce_sum_256(float v) {
    for (int off = 32; off > 0; off >>= 1) v += __shfl_down(v, off, 64);
    __shared__ float red[4];
    __shared__ float tot;
    int lane = threadIdx.x & 63, wid = threadIdx.x >> 6;
    if (lane == 0) red[wid] = v;
    __syncthreads();
    if (threadIdx.x == 0) tot = red[0] + red[1] + red[2] + red[3];
    __syncthreads();
    return tot;
}

// ---------------- weight split (once per launch) ----------------
__global__ __launch_bounds__(256) void cvt_weights(
    const float* __restrict__ rw, const float* __restrict__ sw,
    unsigned short* __restrict__ whi, unsigned short* __restrict__ wlo,
    unsigned short* __restrict__ shi, unsigned short* __restrict__ slo)
{
    int i = blockIdx.x * 256 + threadIdx.x;
    const int nR = D_ * CIN;           // 196608
    const int nS = K_ * D_;            // 16384
    if (i < nR) {
        float x = rw[i];
        unsigned short h = f2bf(x);
        whi[i] = h; wlo[i] = f2bf(x - bf2f(h));
    } else if (i < nR + nS) {
        int j = i - nR;
        float x = sw[j];
        unsigned short h = f2bf(x);
        shi[j] = h; slo[j] = f2bf(x - bf2f(h));
    }
}

// ---------------- 1x1 conv as split-bf16 MFMA GEMM ----------------
// Out[bt][m][p] = sum_k W[m][k]*X[bt][k][p] + bias[m]
// grid (7, 1, 128), block 256 (4 waves). BN=112 (7 frags of 16), BK=32.
// BM=256: wave w owns rows w*64..w*64+63, all 7 n-frags.
// BM=64 : all waves share rows 0..63; wave w owns n-frags {2w, 2w+1} (w3: {6}).
template<int BM>
__global__ __launch_bounds__(256, 2) void mfma_conv1x1(
    const float* __restrict__ X, const unsigned short* __restrict__ Whi,
    const unsigned short* __restrict__ Wlo, const float* __restrict__ bias,
    float* __restrict__ Out, int Kdim)
{
    const int nt = blockIdx.x, bt = blockIdx.z;
    const int p0 = nt * 112;
    const int tid = threadIdx.x, lane = tid & 63, wv = tid >> 6;
    const float* Xb = X + (size_t)bt * Kdim * HW;
    float* Ob = Out + (size_t)bt * BM * HW;

    // rows padded to 40 shorts (80B): 16B-aligned rows, 2-way-max frag-read conflicts
    __shared__ unsigned short lA[2][BM * 40];    // [hi/lo][m][k 0..31]
    __shared__ unsigned short lB[2][112 * 40];   // [hi/lo][n][k 0..31]

    constexpr int NI = (BM == 256) ? 7 : 2;
    floatx4 acc[4][NI];
#pragma unroll
    for (int a = 0; a < 4; ++a)
#pragma unroll
        for (int b = 0; b < NI; ++b) acc[a][b] = (floatx4){0.f, 0.f, 0.f, 0.f};

    const int NKS = Kdim / 32;
    for (int ks = 0; ks < NKS; ++ks) {
        const int k0 = ks * 32;
        // stage A (pre-split bf16 weights): BM*4 chunks of 8 shorts
#pragma unroll
        for (int i = 0; i < BM / 64; ++i) {
            int ch = tid + i * 256;
            int m = ch >> 2, j = ch & 3;
            uint4 hv = *(const uint4*)(Whi + (size_t)m * Kdim + k0 + j * 8);
            uint4 lv = *(const uint4*)(Wlo + (size_t)m * Kdim + k0 + j * 8);
            *(uint4*)&lA[0][m * 40 + j * 8] = hv;
            *(uint4*)&lA[1][m * 40 + j * 8] = lv;
        }
        // stage B transposed, fp32 -> hi/lo in-flight
#pragma unroll
        for (int i = 0; i < 14; ++i) {
            int e = tid + i * 256;                 // 0..3583
            int cc = e / 112, pp = e - cc * 112;
            float xv = Xb[(size_t)(k0 + cc) * HW + p0 + pp];
            unsigned short h = f2bf(xv);
            lB[0][pp * 40 + cc] = h;
            lB[1][pp * 40 + cc] = f2bf(xv - bf2f(h));
        }
        __syncthreads();

        short8 ahi[4], alo[4];
        const int mbase = (BM == 256) ? wv * 64 : 0;
        const int koff = (lane >> 4) * 8;
#pragma unroll
        for (int mi = 0; mi < 4; ++mi) {
            int m = mbase + mi * 16 + (lane & 15);
            ahi[mi] = *(const short8*)&lA[0][m * 40 + koff];
            alo[mi] = *(const short8*)&lA[1][m * 40 + koff];
        }
        if constexpr (BM == 256) {
#pragma unroll
            for (int ni = 0; ni < 7; ++ni) {
                int n = ni * 16 + (lane & 15);
                short8 bhi = *(const short8*)&lB[0][n * 40 + koff];
                short8 blo = *(const short8*)&lB[1][n * 40 + koff];
#pragma unroll
                for (int mi = 0; mi < 4; ++mi) {
                    acc[mi][ni] = __builtin_amdgcn_mfma_f32_16x16x32_bf16(ahi[mi], bhi, acc[mi][ni], 0, 0, 0);
                    acc[mi][ni] = __builtin_amdgcn_mfma_f32_16x16x32_bf16(ahi[mi], blo, acc[mi][ni], 0, 0, 0);
                    acc[mi][ni] = __builtin_amdgcn_mfma_f32_16x16x32_bf16(alo[mi], bhi, acc[mi][ni], 0, 0, 0);
                }
            }
        } else {
#pragma unroll
            for (int nj = 0; nj < 2; ++nj) {
                int ni = wv * 2 + nj;
                if (ni >= 7) break;
                int n = ni * 16 + (lane & 15);
                short8 bhi = *(const short8*)&lB[0][n * 40 + koff];
                short8 blo = *(const short8*)&lB[1][n * 40 + koff];
#pragma unroll
                for (int mi = 0; mi < 4; ++mi) {
                    acc[mi][nj] = __builtin_amdgcn_mfma_f32_16x16x32_bf16(ahi[mi], bhi, acc[mi][nj], 0, 0, 0);
                    acc[mi][nj] = __builtin_amdgcn_mfma_f32_16x16x32_bf16(ahi[mi], blo, acc[mi][nj], 0, 0, 0);
                    acc[mi][nj] = __builtin_amdgcn_mfma_f32_16x16x32_bf16(alo[mi], bhi, acc[mi][nj], 0, 0, 0);
                }
            }
        }
        __syncthreads();
    }

    // epilogue: D row=(lane>>4)*4+r, col=lane&15
    if constexpr (BM == 256) {
#pragma unroll
        for (int mi = 0; mi < 4; ++mi) {
            int m0g = wv * 64 + mi * 16 + ((lane >> 4) << 2);
#pragma unroll
            for (int ni = 0; ni < 7; ++ni) {
                int p = p0 + ni * 16 + (lane & 15);
#pragma unroll
                for (int r = 0; r < 4; ++r)
                    Ob[(size_t)(m0g + r) * HW + p] = acc[mi][ni][r] + bias[m0g + r];
            }
        }
    } else {
#pragma unroll
        for (int nj = 0; nj < 2; ++nj) {
            int ni = wv * 2 + nj;
            if (ni >= 7) break;
            int p = p0 + ni * 16 + (lane & 15);
#pragma unroll
            for (int mi = 0; mi < 4; ++mi) {
                int m0g = mi * 16 + ((lane >> 4) << 2);
#pragma unroll
                for (int r = 0; r < 4; ++r)
                    Ob[(size_t)(m0g + r) * HW + p] = acc[mi][nj][r] + bias[m0g + r];
            }
        }
    }
}

// ---------------- ConvGRU phase A: one gate per block ----------------
// grid (rt=7, kg=8, b+8*gate=16), block 128. gate0: z -> zbuf; gate1: r -> rhbuf=r*h.
__global__ __launch_bounds__(128) void gru_zr(
    const float* __restrict__ hprev, const float* __restrict__ wxb,
    const float* __restrict__ Uz, const float* __restrict__ Ur,
    float* __restrict__ zbuf, float* __restrict__ rhbuf, int t)
{
    int rt = blockIdx.x, kg = blockIdx.y;
    int b = blockIdx.z & 7, gate = blockIdx.z >> 3;
    int k0 = kg * 8, r0 = rt * 4;
    const float* U = gate ? Ur : Uz;
    __shared__ float lh[64 * 6 * 28];     // [c][row(6)][col(28)]
    const float* hb = hprev + (size_t)b * K_ * HW;

    for (int e = threadIdx.x; e < 64 * 6 * 28; e += 128) {
        int c = e / 168; int rem = e - c * 168;
        int rr = rem / 28, col = rem - rr * 28;
        int gr = r0 - 1 + rr;
        lh[e] = (gr >= 0 && gr < 28) ? hb[(size_t)c * HW + gr * 28 + col] : 0.f;
    }
    __syncthreads();

    int tid = threadIdx.x;
    if (tid >= 112) return;
    int pr = tid / 28, pc = tid - pr * 28;

    float acc[8] = {0.f};
#pragma unroll 2
    for (int c = 0; c < 64; ++c) {
        const float* lb = &lh[c * 168 + pr * 28 + pc];
        const float* uu = &U[((size_t)k0 * 64 + c) * 9];
#pragma unroll
        for (int dy = 0; dy < 3; ++dy) {
#pragma unroll
            for (int dx = 0; dx < 3; ++dx) {
                int col = pc + dx - 1;
                float hv = (col >= 0 && col < 28) ? lb[dy * 28 + dx - 1] : 0.f;
                int tap = dy * 3 + dx;
#pragma unroll
                for (int kk = 0; kk < 8; ++kk)
                    acc[kk] = fmaf(hv, uu[kk * 576 + tap], acc[kk]);
            }
        }
    }

    int pidx = (r0 + pr) * 28 + pc;
    int btq = b * T_ + t;
#pragma unroll
    for (int kk = 0; kk < 8; ++kk) {
        int k = k0 + kk;
        float w = wxb[((size_t)btq * K_ + k) * HW + pidx];
        float g = 1.f / (1.f + __expf(-(w + acc[kk])));
        size_t o = ((size_t)b * K_ + k) * HW + pidx;
        if (gate == 0) {
            zbuf[o] = g;
        } else {
            float hp = hb[(size_t)k * HW + pidx];
            rhbuf[o] = g * hp;
        }
    }
}

// ---------------- ConvGRU phase B: candidate conv + update ----------------
__global__ __launch_bounds__(128) void gru_h(
    const float* __restrict__ rh, const float* __restrict__ hprev,
    const float* __restrict__ wxb, const float* __restrict__ Uh,
    const float* __restrict__ zbuf, float* __restrict__ hout, int t)
{
    int rt = blockIdx.x, kg = blockIdx.y, b = blockIdx.z;
    int k0 = kg * 8, r0 = rt * 4;
    __shared__ float lh[64 * 6 * 28];
    const float* rb = rh + (size_t)b * K_ * HW;
    const float* hbp = hprev + (size_t)b * K_ * HW;

    for (int e = threadIdx.x; e < 64 * 6 * 28; e += 128) {
        int c = e / 168; int rem = e - c * 168;
        int rr = rem / 28, col = rem - rr * 28;
        int gr = r0 - 1 + rr;
        lh[e] = (gr >= 0 && gr < 28) ? rb[(size_t)c * HW + gr * 28 + col] : 0.f;
    }
    __syncthreads();

    int tid = threadIdx.x;
    if (tid >= 112) return;
    int pr = tid / 28, pc = tid - pr * 28;

    float acch[8] = {0.f};
#pragma unroll 2
    for (int c = 0; c < 64; ++c) {
        const float* lb = &lh[c * 168 + pr * 28 + pc];
        const float* uh = &Uh[((size_t)k0 * 64 + c) * 9];
#pragma unroll
        for (int dy = 0; dy < 3; ++dy) {
#pragma unroll
            for (int dx = 0; dx < 3; ++dx) {
                int col = pc + dx - 1;
                float hv = (col >= 0 && col < 28) ? lb[dy * 28 + dx - 1] : 0.f;
                int tap = dy * 3 + dx;
#pragma unroll
                for (int kk = 0; kk < 8; ++kk)
                    acch[kk] = fmaf(hv, uh[kk * 576 + tap], acch[kk]);
            }
        }
    }

    int pidx = (r0 + pr) * 28 + pc;
    int btq = b * T_ + t;
#pragma unroll
    for (int kk = 0; kk < 8; ++kk) {
        int k = k0 + kk;
        float w = wxb[((size_t)btq * K_ + k) * HW + pidx];
        float xv = w + acch[kk];
        float e2 = __expf(2.f * xv);
        float th = 1.f - 2.f / (e2 + 1.f);     // tanh
        size_t o = ((size_t)b * K_ + k) * HW + pidx;
        float z = zbuf[o];
        float hp = hbp[(size_t)k * HW + pidx];
        hout[o] = (1.f - z) * th + z * hp;
    }
}

// ---------------- softmax over k (in place on hs) ----------------
__global__ __launch_bounds__(256) void softmax_k(float* __restrict__ hs)
{
    int q = blockIdx.x;
    float* base = hs + (size_t)q * K_ * HW;
    for (int p = threadIdx.x; p < HW; p += 256) {
        float v[64];
        float m = -1e30f;
#pragma unroll
        for (int k = 0; k < 64; ++k) {
            v[k] = base[(size_t)k * HW + p];
            m = fmaxf(m, v[k]);
        }
        float s = 0.f;
#pragma unroll
        for (int k = 0; k < 64; ++k) {
            v[k] = __expf(v[k] - m);
            s += v[k];
        }
        float inv = 1.f / s;
#pragma unroll
        for (int k = 0; k < 64; ++k)
            base[(size_t)k * HW + p] = v[k] * inv;
    }
}

// ---------------- a_sum ----------------
__global__ __launch_bounds__(256) void asum_k(const float* __restrict__ hs,
                                              float* __restrict__ asum)
{
    int bid = blockIdx.x; int b = bid >> 6, k = bid & 63;
    float s = 0.f;
    for (int t = 0; t < T_; ++t) {
        const float* row = hs + (((size_t)t * B_ + b) * K_ + k) * HW;
        for (int p = threadIdx.x; p < HW; p += 256) s += row[p];
    }
    float tot = block_reduce_sum_256(s);
    if (threadIdx.x == 0) asum[bid] = tot;
}

// ---------------- VLAD: per-(b,t) outer-product GEMM ----------------
__global__ __launch_bounds__(256) void vlad_k(const float* __restrict__ assign,
    const float* __restrict__ xr, float* __restrict__ vladt)
{
    int dt = blockIdx.x, t = blockIdx.y, b = blockIdx.z;
    int q = t * B_ + b, bt = b * T_ + t, d0 = dt * 64;
    const float* ab = assign + (size_t)q * K_ * HW;
    const float* xb = xr + (size_t)bt * D_ * HW;
    __shared__ float As[16][68];   // [pp][k]
    __shared__ float Xs[16][68];   // [pp][d]
    int tx = threadIdx.x & 15, ty = threadIdx.x >> 4;
    float acc[4][4] = {{0.f}};

    for (int p0 = 0; p0 < HW; p0 += 16) {
#pragma unroll
        for (int it = 0; it < 4; ++it) {
            int e = threadIdx.x + it * 256;
            int row = e >> 4, pp = e & 15;
            As[pp][row] = ab[(size_t)row * HW + p0 + pp];
            Xs[pp][row] = xb[(size_t)(d0 + row) * HW + p0 + pp];
        }
        __syncthreads();
#pragma unroll
        for (int pp = 0; pp < 16; ++pp) {
            float4 a = *(const float4*)&As[pp][ty * 4];
            float4 xv = *(const float4*)&Xs[pp][tx * 4];
            float av[4] = {a.x, a.y, a.z, a.w};
            float xvv[4] = {xv.x, xv.y, xv.z, xv.w};
#pragma unroll
            for (int r = 0; r < 4; ++r)
#pragma unroll
                for (int s = 0; s < 4; ++s)
                    acc[r][s] = fmaf(av[r], xvv[s], acc[r][s]);
        }
        __syncthreads();
    }
#pragma unroll
    for (int r = 0; r < 4; ++r) {
        int k = ty * 4 + r;
        float4 o = {acc[r][0], acc[r][1], acc[r][2], acc[r][3]};
        *(float4*)&vladt[((size_t)bt * K_ + k) * D_ + d0 + tx * 4] = o;
    }
}

// ---------------- reduce over t, subtract a_sum*centers, intra-norm ----------------
__global__ __launch_bounds__(256) void norm1_k(const float* __restrict__ vladt,
    const float* __restrict__ asum, const float* __restrict__ centers,
    float* __restrict__ out)
{
    int bid = blockIdx.x; int b = bid >> 6, k = bid & 63; int d = threadIdx.x;
    float acc = 0.f;
#pragma unroll
    for (int t = 0; t < T_; ++t)
        acc += vladt[(((size_t)b * T_ + t) * K_ + k) * D_ + d];
    acc -= asum[bid] * centers[(size_t)k * D_ + d];
    float ss = block_reduce_sum_256(acc * acc);
    float n = fmaxf(sqrtf(ss), 1e-12f);
    out[((size_t)b * K_ + k) * D_ + d] = acc / n;
}

// ---------------- global L2 norm per b ----------------
__global__ __launch_bounds__(256) void norm2_k(float* __restrict__ out)
{
    int b = blockIdx.x;
    float* v = out + (size_t)b * (K_ * D_);
    float s = 0.f;
    for (int i = threadIdx.x; i < K_ * D_; i += 256) {
        float x = v[i];
        s = fmaf(x, x, s);
    }
    float tot = block_reduce_sum_256(s);
    float n = fmaxf(sqrtf(tot), 1e-12f);
    for (int i = threadIdx.x; i < K_ * D_; i += 256) v[i] = v[i] / n;
}

// ---------------- launch ----------------
extern "C" void kernel_launch(void* const* d_in, const int* in_sizes, int n_in,
                              void* d_out, int out_size, void* d_ws, size_t ws_size,
                              hipStream_t stream)
{
    const float* x       = (const float*)d_in[0];
    const float* redu_w  = (const float*)d_in[1];
    const float* redu_b  = (const float*)d_in[2];
    const float* share_w = (const float*)d_in[3];
    const float* share_b = (const float*)d_in[4];
    const float* Uz      = (const float*)d_in[5];
    const float* Ur      = (const float*)d_in[6];
    const float* Uh      = (const float*)d_in[7];
    const float* centers = (const float*)d_in[8];

    float* ws = (float*)d_ws;
    const size_t SZ_XR   = (size_t)128 * D_ * HW;
    const size_t SZ_WXB  = (size_t)128 * K_ * HW;
    const size_t SZ_HS   = (size_t)T_ * B_ * K_ * HW;
    const size_t SZ_PLANE= (size_t)B_ * K_ * HW;
    float* xr    = ws;
    float* wxb   = xr + SZ_XR;
    float* hs    = wxb + SZ_WXB;
    float* h0    = hs + SZ_HS;
    float* zbuf  = h0 + SZ_PLANE;
    float* rhbuf = zbuf + SZ_PLANE;
    float* asumb = rhbuf + SZ_PLANE;
    float* vladt = asumb + 512;     // 128*64*256 floats

    // bf16 split weights overlap vladt (weights used before vlad_k writes it)
    unsigned short* whi = (unsigned short*)vladt;
    unsigned short* wlo = whi + D_ * CIN;
    unsigned short* shi = wlo + D_ * CIN;
    unsigned short* slo = shi + K_ * D_;

    hipMemsetAsync(h0, 0, SZ_PLANE * sizeof(float), stream);

    cvt_weights<<<dim3((D_ * CIN + K_ * D_ + 255) / 256), 256, 0, stream>>>(
        redu_w, share_w, whi, wlo, shi, slo);

    // 1) channel reduction (split-bf16 MFMA)
    mfma_conv1x1<256><<<dim3(7, 1, 128), 256, 0, stream>>>(x, whi, wlo, redu_b, xr, CIN);
    // 2) assignment logits
    mfma_conv1x1<64><<<dim3(7, 1, 128), 256, 0, stream>>>(xr, shi, slo, share_b, wxb, D_);

    // 3) ConvGRU over 16 timesteps
    for (int t = 0; t < T_; ++t) {
        const float* hp = (t == 0) ? h0 : hs + (size_t)(t - 1) * SZ_PLANE;
        gru_zr<<<dim3(7, 8, 16), 128, 0, stream>>>(hp, wxb, Uz, Ur, zbuf, rhbuf, t);
        gru_h<<<dim3(7, 8, 8), 128, 0, stream>>>(rhbuf, hp, wxb, Uh, zbuf,
                                                 hs + (size_t)t * SZ_PLANE, t);
    }

    // 4) softmax over centers, a_sum
    softmax_k<<<128, 256, 0, stream>>>(hs);
    asum_k<<<512, 256, 0, stream>>>(hs, asumb);

    // 5) VLAD aggregation + norms
    vlad_k<<<dim3(4, 16, 8), 256, 0, stream>>>(hs, xr, vladt);
    norm1_k<<<512, 256, 0, stream>>>(vladt, asumb, centers, (float*)d_out);
    norm2_k<<<8, 256, 0, stream>>>((float*)d_out);
}

// Round 3
// 795.495 us; speedup vs baseline: 6.5402x; 5.3055x over previous
//
#include <hip/hip_runtime.h>
#include <hip/hip_bf16.h>

#define T_ 16
#define B_ 8
#define CIN 768
#define D_ 256
#define K_ 64
#define HW 784
#define W_ 28

typedef short short8 __attribute__((ext_vector_type(8)));
typedef short short4v __attribute__((ext_vector_type(4)));
typedef float floatx4 __attribute__((ext_vector_type(4)));
typedef unsigned short ushort_t;

// ---------------- bf16 split helpers ----------------
__device__ __forceinline__ unsigned short f2bf(float x) {
    union { float f; unsigned u; } v; v.f = x;
    unsigned u = v.u;
    unsigned r = (u + 0x7fffu + ((u >> 16) & 1u)) >> 16;   // RNE
    return (unsigned short)r;
}
__device__ __forceinline__ float bf2f(unsigned short h) {
    union { unsigned u; float f; } v; v.u = ((unsigned)h) << 16; return v.f;
}

// ---------------- block reduce helper ----------------
__device__ __forceinline__ float block_reduce_sum_256(float v) {
    for (int off = 32; off > 0; off >>= 1) v += __shfl_down(v, off, 64);
    __shared__ float red[4];
    __shared__ float tot;
    int lane = threadIdx.x & 63, wid = threadIdx.x >> 6;
    if (lane == 0) red[wid] = v;
    __syncthreads();
    if (threadIdx.x == 0) tot = red[0] + red[1] + red[2] + red[3];
    __syncthreads();
    return tot;
}

// ---------------- weight split (once per launch) ----------------
// ranges: [0,nR) redu, [nR,nR+nS) share, then Azr (128x576), then Ah (64x576)
__global__ __launch_bounds__(256) void cvt_weights(
    const float* __restrict__ rw, const float* __restrict__ sw,
    const float* __restrict__ Uz, const float* __restrict__ Ur,
    const float* __restrict__ Uh,
    ushort_t* __restrict__ whi, ushort_t* __restrict__ wlo,
    ushort_t* __restrict__ shi, ushort_t* __restrict__ slo,
    ushort_t* __restrict__ azh, ushort_t* __restrict__ azl,
    ushort_t* __restrict__ ahh, ushort_t* __restrict__ ahl)
{
    int i = blockIdx.x * 256 + threadIdx.x;
    const int nR = D_ * CIN;           // 196608
    const int nS = K_ * D_;            // 16384
    const int nZR = 128 * 576;         // 73728
    const int nH = 64 * 576;           // 36864
    if (i < nR) {
        float x = rw[i];
        unsigned short h = f2bf(x);
        whi[i] = h; wlo[i] = f2bf(x - bf2f(h));
    } else if (i < nR + nS) {
        int j = i - nR;
        float x = sw[j];
        unsigned short h = f2bf(x);
        shi[j] = h; slo[j] = f2bf(x - bf2f(h));
    } else if (i < nR + nS + nZR) {
        int j = i - nR - nS;
        int row = j / 576, kk = j - row * 576;
        int tap = kk >> 6, c = kk & 63;
        const float* U = (row < 64) ? Uz : Ur;
        float x = U[(((size_t)(row & 63)) * 64 + c) * 9 + tap];
        unsigned short h = f2bf(x);
        azh[j] = h; azl[j] = f2bf(x - bf2f(h));
    } else if (i < nR + nS + nZR + nH) {
        int j = i - nR - nS - nZR;
        int row = j / 576, kk = j - row * 576;
        int tap = kk >> 6, c = kk & 63;
        float x = Uh[(((size_t)row) * 64 + c) * 9 + tap];
        unsigned short h = f2bf(x);
        ahh[j] = h; ahl[j] = f2bf(x - bf2f(h));
    }
}

// ---------------- 1x1 conv as split-bf16 MFMA GEMM ----------------
template<int BM>
__global__ __launch_bounds__(256, 2) void mfma_conv1x1(
    const float* __restrict__ X, const ushort_t* __restrict__ Whi,
    const ushort_t* __restrict__ Wlo, const float* __restrict__ bias,
    float* __restrict__ Out, int Kdim)
{
    const int nt = blockIdx.x, bt = blockIdx.z;
    const int p0 = nt * 112;
    const int tid = threadIdx.x, lane = tid & 63, wv = tid >> 6;
    const float* Xb = X + (size_t)bt * Kdim * HW;
    float* Ob = Out + (size_t)bt * BM * HW;

    __shared__ ushort_t lA[2][BM * 40];
    __shared__ ushort_t lB[2][112 * 40];

    constexpr int NI = (BM == 256) ? 7 : 2;
    floatx4 acc[4][NI];
#pragma unroll
    for (int a = 0; a < 4; ++a)
#pragma unroll
        for (int b = 0; b < NI; ++b) acc[a][b] = (floatx4){0.f, 0.f, 0.f, 0.f};

    const int NKS = Kdim / 32;
    for (int ks = 0; ks < NKS; ++ks) {
        const int k0 = ks * 32;
#pragma unroll
        for (int i = 0; i < BM / 64; ++i) {
            int ch = tid + i * 256;
            int m = ch >> 2, j = ch & 3;
            uint4 hv = *(const uint4*)(Whi + (size_t)m * Kdim + k0 + j * 8);
            uint4 lv = *(const uint4*)(Wlo + (size_t)m * Kdim + k0 + j * 8);
            *(uint4*)&lA[0][m * 40 + j * 8] = hv;
            *(uint4*)&lA[1][m * 40 + j * 8] = lv;
        }
#pragma unroll
        for (int i = 0; i < 14; ++i) {
            int e = tid + i * 256;
            int cc = e / 112, pp = e - cc * 112;
            float xv = Xb[(size_t)(k0 + cc) * HW + p0 + pp];
            unsigned short h = f2bf(xv);
            lB[0][pp * 40 + cc] = h;
            lB[1][pp * 40 + cc] = f2bf(xv - bf2f(h));
        }
        __syncthreads();

        short8 ahi[4], alo[4];
        const int mbase = (BM == 256) ? wv * 64 : 0;
        const int koff = (lane >> 4) * 8;
#pragma unroll
        for (int mi = 0; mi < 4; ++mi) {
            int m = mbase + mi * 16 + (lane & 15);
            ahi[mi] = *(const short8*)&lA[0][m * 40 + koff];
            alo[mi] = *(const short8*)&lA[1][m * 40 + koff];
        }
        if constexpr (BM == 256) {
#pragma unroll
            for (int ni = 0; ni < 7; ++ni) {
                int n = ni * 16 + (lane & 15);
                short8 bhi = *(const short8*)&lB[0][n * 40 + koff];
                short8 blo = *(const short8*)&lB[1][n * 40 + koff];
#pragma unroll
                for (int mi = 0; mi < 4; ++mi) {
                    acc[mi][ni] = __builtin_amdgcn_mfma_f32_16x16x32_bf16(ahi[mi], bhi, acc[mi][ni], 0, 0, 0);
                    acc[mi][ni] = __builtin_amdgcn_mfma_f32_16x16x32_bf16(ahi[mi], blo, acc[mi][ni], 0, 0, 0);
                    acc[mi][ni] = __builtin_amdgcn_mfma_f32_16x16x32_bf16(alo[mi], bhi, acc[mi][ni], 0, 0, 0);
                }
            }
        } else {
#pragma unroll
            for (int nj = 0; nj < 2; ++nj) {
                int ni = wv * 2 + nj;
                if (ni >= 7) break;
                int n = ni * 16 + (lane & 15);
                short8 bhi = *(const short8*)&lB[0][n * 40 + koff];
                short8 blo = *(const short8*)&lB[1][n * 40 + koff];
#pragma unroll
                for (int mi = 0; mi < 4; ++mi) {
                    acc[mi][nj] = __builtin_amdgcn_mfma_f32_16x16x32_bf16(ahi[mi], bhi, acc[mi][nj], 0, 0, 0);
                    acc[mi][nj] = __builtin_amdgcn_mfma_f32_16x16x32_bf16(ahi[mi], blo, acc[mi][nj], 0, 0, 0);
                    acc[mi][nj] = __builtin_amdgcn_mfma_f32_16x16x32_bf16(alo[mi], bhi, acc[mi][nj], 0, 0, 0);
                }
            }
        }
        __syncthreads();
    }

    if constexpr (BM == 256) {
#pragma unroll
        for (int mi = 0; mi < 4; ++mi) {
            int m0g = wv * 64 + mi * 16 + ((lane >> 4) << 2);
#pragma unroll
            for (int ni = 0; ni < 7; ++ni) {
                int p = p0 + ni * 16 + (lane & 15);
#pragma unroll
                for (int r = 0; r < 4; ++r)
                    Ob[(size_t)(m0g + r) * HW + p] = acc[mi][ni][r] + bias[m0g + r];
            }
        }
    } else {
#pragma unroll
        for (int nj = 0; nj < 2; ++nj) {
            int ni = wv * 2 + nj;
            if (ni >= 7) break;
            int p = p0 + ni * 16 + (lane & 15);
#pragma unroll
            for (int mi = 0; mi < 4; ++mi) {
                int m0g = mi * 16 + ((lane >> 4) << 2);
#pragma unroll
                for (int r = 0; r < 4; ++r)
                    Ob[(size_t)(m0g + r) * HW + p] = acc[mi][nj][r] + bias[m0g + r];
            }
        }
    }
}

// ---------------- GRU staging helper: NHWC split tile -> LDS [6][30][72] ----------------
__device__ __forceinline__ void stage_tile(
    const ushort_t* __restrict__ ghi, const ushort_t* __restrict__ glo,
    ushort_t* Bhi, ushort_t* Blo, int y0, int tid)
{
    for (int e = tid; e < 6 * 30 * 8; e += 256) {
        int r = e / 240, rem = e - r * 240;
        int lx = rem >> 3, j = rem & 7;
        int gy = y0 - 1 + r, gx = lx - 1;
        short8 vh = {0, 0, 0, 0, 0, 0, 0, 0};
        short8 vl = {0, 0, 0, 0, 0, 0, 0, 0};
        if (gy >= 0 && gy < 28 && gx >= 0 && gx < 28) {
            size_t go = ((size_t)(gy * 28 + gx)) * 64 + j * 8;
            vh = *(const short8*)(ghi + go);
            vl = *(const short8*)(glo + go);
        }
        int lo = (r * 30 + lx) * 72 + j * 8;
        *(short8*)&Bhi[lo] = vh;
        *(short8*)&Blo[lo] = vl;
    }
}

// ---------------- GRU conv core: acc[7] += A(64xN half) * im2col(B tile) ----------------
__device__ __forceinline__ void gru_gemm(
    const ushort_t* __restrict__ Ahi, const ushort_t* __restrict__ Alo,
    int arow, int Astride,
    const ushort_t* Bhi, const ushort_t* Blo, int lane, floatx4 acc[7])
{
    const int koff8 = (lane >> 4) * 8;
    const int li = lane & 15;
    int yb[7], xb[7];
#pragma unroll
    for (int nf = 0; nf < 7; ++nf) {
        int pp = nf * 16 + li;
        yb[nf] = pp / 28; xb[nf] = pp - yb[nf] * 28;
    }
    for (int tap = 0; tap < 9; ++tap) {
        int dy = tap / 3, dx = tap - dy * 3;
#pragma unroll
        for (int ch = 0; ch < 2; ++ch) {
            int kk = tap * 64 + ch * 32 + koff8;
            short8 ahi = *(const short8*)(Ahi + (size_t)arow * Astride + kk);
            short8 alo = *(const short8*)(Alo + (size_t)arow * Astride + kk);
            int cbase = ch * 32 + koff8;
#pragma unroll
            for (int nf = 0; nf < 7; ++nf) {
                int o = ((yb[nf] + dy) * 30 + xb[nf] + dx) * 72 + cbase;
                short8 bhi = *(const short8*)&Bhi[o];
                short8 blo = *(const short8*)&Blo[o];
                acc[nf] = __builtin_amdgcn_mfma_f32_16x16x32_bf16(ahi, bhi, acc[nf], 0, 0, 0);
                acc[nf] = __builtin_amdgcn_mfma_f32_16x16x32_bf16(ahi, blo, acc[nf], 0, 0, 0);
                acc[nf] = __builtin_amdgcn_mfma_f32_16x16x32_bf16(alo, bhi, acc[nf], 0, 0, 0);
            }
        }
    }
}

// ---------------- GRU phase A: z (half 0) / r (half 1) gate, MFMA ----------------
// grid (7 rowchunks, 8 b, 2 halves), block 256 (4 waves; wave = m-frag).
__global__ __launch_bounds__(256, 2) void gru_zr_mfma(
    const ushort_t* __restrict__ hhi, const ushort_t* __restrict__ hlo,
    const ushort_t* __restrict__ azh, const ushort_t* __restrict__ azl,
    const float* __restrict__ wxb, const float* __restrict__ hprev_f,
    float* __restrict__ zbuf, ushort_t* __restrict__ rhi, ushort_t* __restrict__ rlo,
    int t)
{
    int rt = blockIdx.x, b = blockIdx.y, half = blockIdx.z;
    int y0 = rt * 4;
    int tid = threadIdx.x, lane = tid & 63, wv = tid >> 6;

    __shared__ ushort_t Bhi[6 * 30 * 72];
    __shared__ ushort_t Blo[6 * 30 * 72];
    stage_tile(hhi + (size_t)b * HW * 64, hlo + (size_t)b * HW * 64, Bhi, Blo, y0, tid);
    __syncthreads();

    floatx4 acc[7];
#pragma unroll
    for (int nf = 0; nf < 7; ++nf) acc[nf] = (floatx4){0.f, 0.f, 0.f, 0.f};

    int arow = half * 64 + wv * 16 + (lane & 15);
    gru_gemm(azh, azl, arow, 576, Bhi, Blo, lane, acc);

    // epilogue
    int kbase = wv * 16 + ((lane >> 4) << 2);
    const float* wx = wxb + (((size_t)b * T_ + t) * K_) * HW;
    const float* hp = hprev_f + (size_t)b * K_ * HW;
#pragma unroll
    for (int nf = 0; nf < 7; ++nf) {
        int p = y0 * 28 + nf * 16 + (lane & 15);
        if (half == 0) {
#pragma unroll
            for (int r = 0; r < 4; ++r) {
                int k = kbase + r;
                float g = 1.f / (1.f + __expf(-(wx[(size_t)k * HW + p] + acc[nf][r])));
                zbuf[((size_t)b * K_ + k) * HW + p] = g;
            }
        } else {
            short4v vh, vl;
#pragma unroll
            for (int r = 0; r < 4; ++r) {
                int k = kbase + r;
                float g = 1.f / (1.f + __expf(-(wx[(size_t)k * HW + p] + acc[nf][r])));
                float rh = g * hp[(size_t)k * HW + p];
                unsigned short h = f2bf(rh);
                vh[r] = h; vl[r] = f2bf(rh - bf2f(h));
            }
            size_t o = (size_t)(b * HW + p) * 64 + kbase;
            *(short4v*)(rhi + o) = vh;
            *(short4v*)(rlo + o) = vl;
        }
    }
}

// ---------------- GRU phase B: candidate + state update, MFMA ----------------
// grid (7 rowchunks, 8 b), block 256 (4 waves; wave = m-frag).
__global__ __launch_bounds__(256, 2) void gru_h_mfma(
    const ushort_t* __restrict__ rhi, const ushort_t* __restrict__ rlo,
    const ushort_t* __restrict__ ahh, const ushort_t* __restrict__ ahl,
    const float* __restrict__ wxb, const float* __restrict__ hprev_f,
    const float* __restrict__ zbuf, float* __restrict__ hs_t,
    ushort_t* __restrict__ hhi, ushort_t* __restrict__ hlo, int t)
{
    int rt = blockIdx.x, b = blockIdx.y;
    int y0 = rt * 4;
    int tid = threadIdx.x, lane = tid & 63, wv = tid >> 6;

    __shared__ ushort_t Bhi[6 * 30 * 72];
    __shared__ ushort_t Blo[6 * 30 * 72];
    stage_tile(rhi + (size_t)b * HW * 64, rlo + (size_t)b * HW * 64, Bhi, Blo, y0, tid);
    __syncthreads();

    floatx4 acc[7];
#pragma unroll
    for (int nf = 0; nf < 7; ++nf) acc[nf] = (floatx4){0.f, 0.f, 0.f, 0.f};

    int arow = wv * 16 + (lane & 15);
    gru_gemm(ahh, ahl, arow, 576, Bhi, Blo, lane, acc);

    int kbase = wv * 16 + ((lane >> 4) << 2);
    const float* wx = wxb + (((size_t)b * T_ + t) * K_) * HW;
    const float* hp = hprev_f + (size_t)b * K_ * HW;
#pragma unroll
    for (int nf = 0; nf < 7; ++nf) {
        int p = y0 * 28 + nf * 16 + (lane & 15);
        short4v vh, vl;
#pragma unroll
        for (int r = 0; r < 4; ++r) {
            int k = kbase + r;
            float xv = wx[(size_t)k * HW + p] + acc[nf][r];
            float e2 = __expf(2.f * xv);
            float th = 1.f - 2.f / (e2 + 1.f);
            float z = zbuf[((size_t)b * K_ + k) * HW + p];
            float hpv = hp[(size_t)k * HW + p];
            float hn = (1.f - z) * th + z * hpv;
            hs_t[((size_t)b * K_ + k) * HW + p] = hn;
            unsigned short h = f2bf(hn);
            vh[r] = h; vl[r] = f2bf(hn - bf2f(h));
        }
        size_t o = (size_t)(b * HW + p) * 64 + kbase;
        *(short4v*)(hhi + o) = vh;
        *(short4v*)(hlo + o) = vl;
    }
}

// ---------------- softmax over k (in place on hs) ----------------
__global__ __launch_bounds__(256) void softmax_k(float* __restrict__ hs)
{
    int q = blockIdx.x;
    float* base = hs + (size_t)q * K_ * HW;
    for (int p = threadIdx.x; p < HW; p += 256) {
        float v[64];
        float m = -1e30f;
#pragma unroll
        for (int k = 0; k < 64; ++k) {
            v[k] = base[(size_t)k * HW + p];
            m = fmaxf(m, v[k]);
        }
        float s = 0.f;
#pragma unroll
        for (int k = 0; k < 64; ++k) {
            v[k] = __expf(v[k] - m);
            s += v[k];
        }
        float inv = 1.f / s;
#pragma unroll
        for (int k = 0; k < 64; ++k)
            base[(size_t)k * HW + p] = v[k] * inv;
    }
}

// ---------------- a_sum ----------------
__global__ __launch_bounds__(256) void asum_k(const float* __restrict__ hs,
                                              float* __restrict__ asum)
{
    int bid = blockIdx.x; int b = bid >> 6, k = bid & 63;
    float s = 0.f;
    for (int t = 0; t < T_; ++t) {
        const float* row = hs + (((size_t)t * B_ + b) * K_ + k) * HW;
        for (int p = threadIdx.x; p < HW; p += 256) s += row[p];
    }
    float tot = block_reduce_sum_256(s);
    if (threadIdx.x == 0) asum[bid] = tot;
}

// ---------------- VLAD: per-(b,t) outer-product GEMM ----------------
__global__ __launch_bounds__(256) void vlad_k(const float* __restrict__ assign,
    const float* __restrict__ xr, float* __restrict__ vladt)
{
    int dt = blockIdx.x, t = blockIdx.y, b = blockIdx.z;
    int q = t * B_ + b, bt = b * T_ + t, d0 = dt * 64;
    const float* ab = assign + (size_t)q * K_ * HW;
    const float* xb = xr + (size_t)bt * D_ * HW;
    __shared__ float As[16][68];
    __shared__ float Xs[16][68];
    int tx = threadIdx.x & 15, ty = threadIdx.x >> 4;
    float acc[4][4] = {{0.f}};

    for (int p0 = 0; p0 < HW; p0 += 16) {
#pragma unroll
        for (int it = 0; it < 4; ++it) {
            int e = threadIdx.x + it * 256;
            int row = e >> 4, pp = e & 15;
            As[pp][row] = ab[(size_t)row * HW + p0 + pp];
            Xs[pp][row] = xb[(size_t)(d0 + row) * HW + p0 + pp];
        }
        __syncthreads();
#pragma unroll
        for (int pp = 0; pp < 16; ++pp) {
            float4 a = *(const float4*)&As[pp][ty * 4];
            float4 xv = *(const float4*)&Xs[pp][tx * 4];
            float av[4] = {a.x, a.y, a.z, a.w};
            float xvv[4] = {xv.x, xv.y, xv.z, xv.w};
#pragma unroll
            for (int r = 0; r < 4; ++r)
#pragma unroll
                for (int s = 0; s < 4; ++s)
                    acc[r][s] = fmaf(av[r], xvv[s], acc[r][s]);
        }
        __syncthreads();
    }
#pragma unroll
    for (int r = 0; r < 4; ++r) {
        int k = ty * 4 + r;
        float4 o = {acc[r][0], acc[r][1], acc[r][2], acc[r][3]};
        *(float4*)&vladt[((size_t)bt * K_ + k) * D_ + d0 + tx * 4] = o;
    }
}

// ---------------- reduce over t, subtract a_sum*centers, intra-norm ----------------
__global__ __launch_bounds__(256) void norm1_k(const float* __restrict__ vladt,
    const float* __restrict__ asum, const float* __restrict__ centers,
    float* __restrict__ out)
{
    int bid = blockIdx.x; int b = bid >> 6, k = bid & 63; int d = threadIdx.x;
    float acc = 0.f;
#pragma unroll
    for (int t = 0; t < T_; ++t)
        acc += vladt[(((size_t)b * T_ + t) * K_ + k) * D_ + d];
    acc -= asum[bid] * centers[(size_t)k * D_ + d];
    float ss = block_reduce_sum_256(acc * acc);
    float n = fmaxf(sqrtf(ss), 1e-12f);
    out[((size_t)b * K_ + k) * D_ + d] = acc / n;
}

// ---------------- global L2 norm per b ----------------
__global__ __launch_bounds__(256) void norm2_k(float* __restrict__ out)
{
    int b = blockIdx.x;
    float* v = out + (size_t)b * (K_ * D_);
    float s = 0.f;
    for (int i = threadIdx.x; i < K_ * D_; i += 256) {
        float x = v[i];
        s = fmaf(x, x, s);
    }
    float tot = block_reduce_sum_256(s);
    float n = fmaxf(sqrtf(tot), 1e-12f);
    for (int i = threadIdx.x; i < K_ * D_; i += 256) v[i] = v[i] / n;
}

// ---------------- launch ----------------
extern "C" void kernel_launch(void* const* d_in, const int* in_sizes, int n_in,
                              void* d_out, int out_size, void* d_ws, size_t ws_size,
                              hipStream_t stream)
{
    const float* x       = (const float*)d_in[0];
    const float* redu_w  = (const float*)d_in[1];
    const float* redu_b  = (const float*)d_in[2];
    const float* share_w = (const float*)d_in[3];
    const float* share_b = (const float*)d_in[4];
    const float* Uz      = (const float*)d_in[5];
    const float* Ur      = (const float*)d_in[6];
    const float* Uh      = (const float*)d_in[7];
    const float* centers = (const float*)d_in[8];

    float* ws = (float*)d_ws;
    const size_t SZ_XR   = (size_t)128 * D_ * HW;       // 25,690,112
    const size_t SZ_WXB  = (size_t)128 * K_ * HW;       //  6,422,528
    const size_t SZ_HS   = (size_t)T_ * B_ * K_ * HW;   //  6,422,528
    const size_t SZ_PLANE= (size_t)B_ * K_ * HW;        //    401,408

    float* xr    = ws;
    float* wxb   = xr + SZ_XR;
    float* hs    = wxb + SZ_WXB;
    float* h0    = hs + SZ_HS;
    float* zbuf  = h0 + SZ_PLANE;
    float* asumb = zbuf + SZ_PLANE;          // 512 floats
    float* wsplit= asumb + 512;              // 323,584 floats of split weights
    float* area  = wsplit + 323584;          // union: vladt | GRU split buffers

    // split weights (shorts)
    ushort_t* whi = (ushort_t*)wsplit;            // 196608
    ushort_t* wlo = whi + 196608;
    ushort_t* shi = wlo + 196608;                 // 16384
    ushort_t* slo = shi + 16384;
    ushort_t* azh = slo + 16384;                  // 73728
    ushort_t* azl = azh + 73728;
    ushort_t* ahh = azl + 73728;                  // 36864
    ushort_t* ahl = ahh + 36864;

    // GRU split state (NHWC) + vladt share the same region (disjoint lifetimes)
    float* vladt = area;                          // 2,097,152 floats
    ushort_t* hhi = (ushort_t*)area;              // 401,408 shorts
    ushort_t* hlo = hhi + SZ_PLANE;
    ushort_t* rhi = hlo + SZ_PLANE;
    ushort_t* rlo = rhi + SZ_PLANE;               // total 1,605,632 shorts < vladt bytes

    hipMemsetAsync(h0, 0, SZ_PLANE * sizeof(float), stream);
    hipMemsetAsync(hhi, 0, 2 * SZ_PLANE * sizeof(ushort_t), stream);  // hhi+hlo

    cvt_weights<<<dim3((D_ * CIN + K_ * D_ + 128 * 576 + 64 * 576 + 255) / 256),
                  256, 0, stream>>>(redu_w, share_w, Uz, Ur, Uh,
                                    whi, wlo, shi, slo, azh, azl, ahh, ahl);

    // 1) channel reduction (split-bf16 MFMA)
    mfma_conv1x1<256><<<dim3(7, 1, 128), 256, 0, stream>>>(x, whi, wlo, redu_b, xr, CIN);
    // 2) assignment logits
    mfma_conv1x1<64><<<dim3(7, 1, 128), 256, 0, stream>>>(xr, shi, slo, share_b, wxb, D_);

    // 3) ConvGRU over 16 timesteps (MFMA implicit GEMM)
    for (int t = 0; t < T_; ++t) {
        const float* hp = (t == 0) ? h0 : hs + (size_t)(t - 1) * SZ_PLANE;
        gru_zr_mfma<<<dim3(7, 8, 2), 256, 0, stream>>>(hhi, hlo, azh, azl, wxb, hp,
                                                       zbuf, rhi, rlo, t);
        gru_h_mfma<<<dim3(7, 8), 256, 0, stream>>>(rhi, rlo, ahh, ahl, wxb, hp, zbuf,
                                                   hs + (size_t)t * SZ_PLANE, hhi, hlo, t);
    }

    // 4) softmax over centers, a_sum
    softmax_k<<<128, 256, 0, stream>>>(hs);
    asum_k<<<512, 256, 0, stream>>>(hs, asumb);

    // 5) VLAD aggregation + norms
    vlad_k<<<dim3(4, 16, 8), 256, 0, stream>>>(hs, xr, vladt);
    norm1_k<<<512, 256, 0, stream>>>(vladt, asumb, centers, (float*)d_out);
    norm2_k<<<8, 256, 0, stream>>>((float*)d_out);
}

// Round 4
// 791.700 us; speedup vs baseline: 6.5716x; 1.0048x over previous
//
#include <hip/hip_runtime.h>
#include <hip/hip_bf16.h>

#define T_ 16
#define B_ 8
#define CIN 768
#define D_ 256
#define K_ 64
#define HW 784
#define W_ 28

typedef short short8 __attribute__((ext_vector_type(8)));
typedef short short4v __attribute__((ext_vector_type(4)));
typedef float floatx4 __attribute__((ext_vector_type(4)));
typedef unsigned short ushort_t;

// ---------------- bf16 split helpers ----------------
__device__ __forceinline__ unsigned short f2bf(float x) {
    union { float f; unsigned u; } v; v.f = x;
    unsigned u = v.u;
    unsigned r = (u + 0x7fffu + ((u >> 16) & 1u)) >> 16;   // RNE
    return (unsigned short)r;
}
__device__ __forceinline__ float bf2f(unsigned short h) {
    union { unsigned u; float f; } v; v.u = ((unsigned)h) << 16; return v.f;
}

// ---------------- block reduce helper ----------------
__device__ __forceinline__ float block_reduce_sum_256(float v) {
    for (int off = 32; off > 0; off >>= 1) v += __shfl_down(v, off, 64);
    __shared__ float red[4];
    __shared__ float tot;
    int lane = threadIdx.x & 63, wid = threadIdx.x >> 6;
    if (lane == 0) red[wid] = v;
    __syncthreads();
    if (threadIdx.x == 0) tot = red[0] + red[1] + red[2] + red[3];
    __syncthreads();
    return tot;
}

// ---------------- weight split (once per launch) ----------------
__global__ __launch_bounds__(256) void cvt_weights(
    const float* __restrict__ rw, const float* __restrict__ sw,
    const float* __restrict__ Uz, const float* __restrict__ Ur,
    const float* __restrict__ Uh,
    ushort_t* __restrict__ whi, ushort_t* __restrict__ wlo,
    ushort_t* __restrict__ shi, ushort_t* __restrict__ slo,
    ushort_t* __restrict__ azh, ushort_t* __restrict__ azl,
    ushort_t* __restrict__ ahh, ushort_t* __restrict__ ahl)
{
    int i = blockIdx.x * 256 + threadIdx.x;
    const int nR = D_ * CIN;           // 196608
    const int nS = K_ * D_;            // 16384
    const int nZR = 128 * 576;         // 73728
    const int nH = 64 * 576;           // 36864
    if (i < nR) {
        float x = rw[i];
        unsigned short h = f2bf(x);
        whi[i] = h; wlo[i] = f2bf(x - bf2f(h));
    } else if (i < nR + nS) {
        int j = i - nR;
        float x = sw[j];
        unsigned short h = f2bf(x);
        shi[j] = h; slo[j] = f2bf(x - bf2f(h));
    } else if (i < nR + nS + nZR) {
        int j = i - nR - nS;
        int row = j / 576, kk = j - row * 576;
        int tap = kk >> 6, c = kk & 63;
        const float* U = (row < 64) ? Uz : Ur;
        float x = U[(((size_t)(row & 63)) * 64 + c) * 9 + tap];
        unsigned short h = f2bf(x);
        azh[j] = h; azl[j] = f2bf(x - bf2f(h));
    } else if (i < nR + nS + nZR + nH) {
        int j = i - nR - nS - nZR;
        int row = j / 576, kk = j - row * 576;
        int tap = kk >> 6, c = kk & 63;
        float x = Uh[(((size_t)row) * 64 + c) * 9 + tap];
        unsigned short h = f2bf(x);
        ahh[j] = h; ahl[j] = f2bf(x - bf2f(h));
    }
}

// ---------------- 1x1 conv as split-bf16 MFMA GEMM (v2) ----------------
// A-frags direct from global (L2-resident split weights); B staged to LDS
// via 8-channel packs -> conflict-free ds_write_b128.
// grid (7, 1, 128), block 256 (4 waves). BN=112, BK=32.
template<int BM, int MINW>
__global__ __launch_bounds__(256, MINW) void mfma_conv1x1(
    const float* __restrict__ X, const ushort_t* __restrict__ Whi,
    const ushort_t* __restrict__ Wlo, const float* __restrict__ bias,
    float* __restrict__ Out, int Kdim)
{
    const int nt = blockIdx.x, bt = blockIdx.z;
    const int p0 = nt * 112;
    const int tid = threadIdx.x, lane = tid & 63, wv = tid >> 6;
    const float* Xb = X + (size_t)bt * Kdim * HW;
    float* Ob = Out + (size_t)bt * BM * HW;

    __shared__ ushort_t lB[2][112 * 40];   // [hi/lo][pp][k 0..31] rows padded to 40

    constexpr int NI = (BM == 256) ? 7 : 2;
    floatx4 acc[4][NI];
#pragma unroll
    for (int a = 0; a < 4; ++a)
#pragma unroll
        for (int b = 0; b < NI; ++b) acc[a][b] = (floatx4){0.f, 0.f, 0.f, 0.f};

    const int koff = (lane >> 4) * 8;
    const int mbase = (BM == 256) ? wv * 64 : 0;

    const int NKS = Kdim / 32;
    for (int ks = 0; ks < NKS; ++ks) {
        const int k0 = ks * 32;
        // stage B: 448 units (pp, j-group of 8 channels)
#pragma unroll
        for (int u = tid; u < 448; u += 256) {
            int j = u / 112, pp = u - j * 112;
            const float* xp = Xb + (size_t)(k0 + j * 8) * HW + p0 + pp;
            short8 vh, vl;
#pragma unroll
            for (int c = 0; c < 8; ++c) {
                float xv = xp[(size_t)c * HW];
                unsigned short h = f2bf(xv);
                vh[c] = (short)h;
                vl[c] = (short)f2bf(xv - bf2f(h));
            }
            *(short8*)&lB[0][pp * 40 + j * 8] = vh;
            *(short8*)&lB[1][pp * 40 + j * 8] = vl;
        }
        __syncthreads();

        // A-frags straight from L2
        short8 ahi[4], alo[4];
#pragma unroll
        for (int mi = 0; mi < 4; ++mi) {
            int m = mbase + mi * 16 + (lane & 15);
            ahi[mi] = *(const short8*)(Whi + (size_t)m * Kdim + k0 + koff);
            alo[mi] = *(const short8*)(Wlo + (size_t)m * Kdim + k0 + koff);
        }
        if constexpr (BM == 256) {
#pragma unroll
            for (int ni = 0; ni < 7; ++ni) {
                int n = ni * 16 + (lane & 15);
                short8 bhi = *(const short8*)&lB[0][n * 40 + koff];
                short8 blo = *(const short8*)&lB[1][n * 40 + koff];
#pragma unroll
                for (int mi = 0; mi < 4; ++mi) {
                    acc[mi][ni] = __builtin_amdgcn_mfma_f32_16x16x32_bf16(ahi[mi], bhi, acc[mi][ni], 0, 0, 0);
                    acc[mi][ni] = __builtin_amdgcn_mfma_f32_16x16x32_bf16(ahi[mi], blo, acc[mi][ni], 0, 0, 0);
                    acc[mi][ni] = __builtin_amdgcn_mfma_f32_16x16x32_bf16(alo[mi], bhi, acc[mi][ni], 0, 0, 0);
                }
            }
        } else {
#pragma unroll
            for (int nj = 0; nj < 2; ++nj) {
                int ni = wv * 2 + nj;
                if (ni >= 7) break;
                int n = ni * 16 + (lane & 15);
                short8 bhi = *(const short8*)&lB[0][n * 40 + koff];
                short8 blo = *(const short8*)&lB[1][n * 40 + koff];
#pragma unroll
                for (int mi = 0; mi < 4; ++mi) {
                    acc[mi][nj] = __builtin_amdgcn_mfma_f32_16x16x32_bf16(ahi[mi], bhi, acc[mi][nj], 0, 0, 0);
                    acc[mi][nj] = __builtin_amdgcn_mfma_f32_16x16x32_bf16(ahi[mi], blo, acc[mi][nj], 0, 0, 0);
                    acc[mi][nj] = __builtin_amdgcn_mfma_f32_16x16x32_bf16(alo[mi], bhi, acc[mi][nj], 0, 0, 0);
                }
            }
        }
        __syncthreads();
    }

    if constexpr (BM == 256) {
#pragma unroll
        for (int mi = 0; mi < 4; ++mi) {
            int m0g = wv * 64 + mi * 16 + ((lane >> 4) << 2);
#pragma unroll
            for (int ni = 0; ni < 7; ++ni) {
                int p = p0 + ni * 16 + (lane & 15);
#pragma unroll
                for (int r = 0; r < 4; ++r)
                    Ob[(size_t)(m0g + r) * HW + p] = acc[mi][ni][r] + bias[m0g + r];
            }
        }
    } else {
#pragma unroll
        for (int nj = 0; nj < 2; ++nj) {
            int ni = wv * 2 + nj;
            if (ni >= 7) break;
            int p = p0 + ni * 16 + (lane & 15);
#pragma unroll
            for (int mi = 0; mi < 4; ++mi) {
                int m0g = mi * 16 + ((lane >> 4) << 2);
#pragma unroll
                for (int r = 0; r < 4; ++r)
                    Ob[(size_t)(m0g + r) * HW + p] = acc[mi][nj][r] + bias[m0g + r];
            }
        }
    }
}

// ---------------- GRU staging: NHWC split 3-row tile -> LDS [3][30][72] ----------------
__device__ __forceinline__ void stage_tile3(
    const ushort_t* __restrict__ ghi, const ushort_t* __restrict__ glo,
    ushort_t* Bhi, ushort_t* Blo, int y0, int tid)
{
    for (int e = tid; e < 3 * 30 * 8; e += 256) {
        int r = e / 240, rem = e - r * 240;
        int lx = rem >> 3, j = rem & 7;
        int gy = y0 - 1 + r, gx = lx - 1;
        short8 vh = {0, 0, 0, 0, 0, 0, 0, 0};
        short8 vl = {0, 0, 0, 0, 0, 0, 0, 0};
        if (gy >= 0 && gy < 28 && gx >= 0 && gx < 28) {
            size_t go = ((size_t)(gy * 28 + gx)) * 64 + j * 8;
            vh = *(const short8*)(ghi + go);
            vl = *(const short8*)(glo + go);
        }
        int lo = (r * 30 + lx) * 72 + j * 8;
        *(short8*)&Bhi[lo] = vh;
        *(short8*)&Blo[lo] = vl;
    }
}

// ---------------- GRU conv core (rowchunk=1): acc[2] over 28 positions ----------------
__device__ __forceinline__ void gru_gemm1(
    const ushort_t* __restrict__ Ahi, const ushort_t* __restrict__ Alo, int arow,
    const ushort_t* Bhi, const ushort_t* Blo, int lane, floatx4 acc[2])
{
    const int koff8 = (lane >> 4) * 8;
    const int li = lane & 15;
    const int xb0 = li;
    const int xb1 = (li < 12) ? 16 + li : 0;   // clamp invalid cols
#pragma unroll
    for (int tap = 0; tap < 9; ++tap) {
        const int dy = tap / 3, dx = tap - dy * 3;
#pragma unroll
        for (int ch = 0; ch < 2; ++ch) {
            int kk = tap * 64 + ch * 32 + koff8;
            short8 ahi = *(const short8*)(Ahi + (size_t)arow * 576 + kk);
            short8 alo = *(const short8*)(Alo + (size_t)arow * 576 + kk);
            int cbase = ch * 32 + koff8;
            int o0 = (dy * 30 + xb0 + dx) * 72 + cbase;
            int o1 = (dy * 30 + xb1 + dx) * 72 + cbase;
            short8 bhi0 = *(const short8*)&Bhi[o0];
            short8 blo0 = *(const short8*)&Blo[o0];
            short8 bhi1 = *(const short8*)&Bhi[o1];
            short8 blo1 = *(const short8*)&Blo[o1];
            acc[0] = __builtin_amdgcn_mfma_f32_16x16x32_bf16(ahi, bhi0, acc[0], 0, 0, 0);
            acc[0] = __builtin_amdgcn_mfma_f32_16x16x32_bf16(ahi, blo0, acc[0], 0, 0, 0);
            acc[0] = __builtin_amdgcn_mfma_f32_16x16x32_bf16(alo, bhi0, acc[0], 0, 0, 0);
            acc[1] = __builtin_amdgcn_mfma_f32_16x16x32_bf16(ahi, bhi1, acc[1], 0, 0, 0);
            acc[1] = __builtin_amdgcn_mfma_f32_16x16x32_bf16(ahi, blo1, acc[1], 0, 0, 0);
            acc[1] = __builtin_amdgcn_mfma_f32_16x16x32_bf16(alo, bhi1, acc[1], 0, 0, 0);
        }
    }
}

// ---------------- GRU phase A: z (half 0) / r (half 1), rowchunk=1 ----------------
// grid (28, 8, 2), block 256.
__global__ __launch_bounds__(256, 4) void gru_zr_mfma(
    const ushort_t* __restrict__ hhi, const ushort_t* __restrict__ hlo,
    const ushort_t* __restrict__ azh, const ushort_t* __restrict__ azl,
    const float* __restrict__ wxb, const float* __restrict__ hprev_f,
    float* __restrict__ zbuf, ushort_t* __restrict__ rhi, ushort_t* __restrict__ rlo,
    int t)
{
    int y0 = blockIdx.x, b = blockIdx.y, half = blockIdx.z;
    int tid = threadIdx.x, lane = tid & 63, wv = tid >> 6;

    __shared__ ushort_t Bhi[3 * 30 * 72];
    __shared__ ushort_t Blo[3 * 30 * 72];
    stage_tile3(hhi + (size_t)b * HW * 64, hlo + (size_t)b * HW * 64, Bhi, Blo, y0, tid);
    __syncthreads();

    floatx4 acc[2];
    acc[0] = (floatx4){0.f, 0.f, 0.f, 0.f};
    acc[1] = (floatx4){0.f, 0.f, 0.f, 0.f};

    int arow = half * 64 + wv * 16 + (lane & 15);
    gru_gemm1(azh, azl, arow, Bhi, Blo, lane, acc);

    int li = lane & 15;
    int kbase = wv * 16 + ((lane >> 4) << 2);
    const float* wx = wxb + (((size_t)b * T_ + t) * K_) * HW;
    const float* hp = hprev_f + (size_t)b * K_ * HW;
#pragma unroll
    for (int nf = 0; nf < 2; ++nf) {
        int pp = nf * 16 + li;
        if (pp >= 28) break;
        int p = y0 * 28 + pp;
        if (half == 0) {
#pragma unroll
            for (int r = 0; r < 4; ++r) {
                int k = kbase + r;
                float g = 1.f / (1.f + __expf(-(wx[(size_t)k * HW + p] + acc[nf][r])));
                zbuf[((size_t)b * K_ + k) * HW + p] = g;
            }
        } else {
            short4v vh, vl;
#pragma unroll
            for (int r = 0; r < 4; ++r) {
                int k = kbase + r;
                float g = 1.f / (1.f + __expf(-(wx[(size_t)k * HW + p] + acc[nf][r])));
                float rh = g * hp[(size_t)k * HW + p];
                unsigned short h = f2bf(rh);
                vh[r] = h; vl[r] = f2bf(rh - bf2f(h));
            }
            size_t o = (size_t)(b * HW + p) * 64 + kbase;
            *(short4v*)(rhi + o) = vh;
            *(short4v*)(rlo + o) = vl;
        }
    }
}

// ---------------- GRU phase B: candidate + update, rowchunk=1 ----------------
// grid (28, 8), block 256.
__global__ __launch_bounds__(256, 4) void gru_h_mfma(
    const ushort_t* __restrict__ rhi, const ushort_t* __restrict__ rlo,
    const ushort_t* __restrict__ ahh, const ushort_t* __restrict__ ahl,
    const float* __restrict__ wxb, const float* __restrict__ hprev_f,
    const float* __restrict__ zbuf, float* __restrict__ hs_t,
    ushort_t* __restrict__ hhi, ushort_t* __restrict__ hlo, int t)
{
    int y0 = blockIdx.x, b = blockIdx.y;
    int tid = threadIdx.x, lane = tid & 63, wv = tid >> 6;

    __shared__ ushort_t Bhi[3 * 30 * 72];
    __shared__ ushort_t Blo[3 * 30 * 72];
    stage_tile3(rhi + (size_t)b * HW * 64, rlo + (size_t)b * HW * 64, Bhi, Blo, y0, tid);
    __syncthreads();

    floatx4 acc[2];
    acc[0] = (floatx4){0.f, 0.f, 0.f, 0.f};
    acc[1] = (floatx4){0.f, 0.f, 0.f, 0.f};

    int arow = wv * 16 + (lane & 15);
    gru_gemm1(ahh, ahl, arow, Bhi, Blo, lane, acc);

    int li = lane & 15;
    int kbase = wv * 16 + ((lane >> 4) << 2);
    const float* wx = wxb + (((size_t)b * T_ + t) * K_) * HW;
    const float* hp = hprev_f + (size_t)b * K_ * HW;
#pragma unroll
    for (int nf = 0; nf < 2; ++nf) {
        int pp = nf * 16 + li;
        if (pp >= 28) break;
        int p = y0 * 28 + pp;
        short4v vh, vl;
#pragma unroll
        for (int r = 0; r < 4; ++r) {
            int k = kbase + r;
            float xv = wx[(size_t)k * HW + p] + acc[nf][r];
            float e2 = __expf(2.f * xv);
            float th = 1.f - 2.f / (e2 + 1.f);
            float z = zbuf[((size_t)b * K_ + k) * HW + p];
            float hpv = hp[(size_t)k * HW + p];
            float hn = (1.f - z) * th + z * hpv;
            hs_t[((size_t)b * K_ + k) * HW + p] = hn;
            unsigned short h = f2bf(hn);
            vh[r] = h; vl[r] = f2bf(hn - bf2f(h));
        }
        size_t o = (size_t)(b * HW + p) * 64 + kbase;
        *(short4v*)(hhi + o) = vh;
        *(short4v*)(hlo + o) = vl;
    }
}

// ---------------- softmax over k (in place on hs) ----------------
__global__ __launch_bounds__(256) void softmax_k(float* __restrict__ hs)
{
    int q = blockIdx.x;
    float* base = hs + (size_t)q * K_ * HW;
    for (int p = threadIdx.x; p < HW; p += 256) {
        float v[64];
        float m = -1e30f;
#pragma unroll
        for (int k = 0; k < 64; ++k) {
            v[k] = base[(size_t)k * HW + p];
            m = fmaxf(m, v[k]);
        }
        float s = 0.f;
#pragma unroll
        for (int k = 0; k < 64; ++k) {
            v[k] = __expf(v[k] - m);
            s += v[k];
        }
        float inv = 1.f / s;
#pragma unroll
        for (int k = 0; k < 64; ++k)
            base[(size_t)k * HW + p] = v[k] * inv;
    }
}

// ---------------- a_sum ----------------
__global__ __launch_bounds__(256) void asum_k(const float* __restrict__ hs,
                                              float* __restrict__ asum)
{
    int bid = blockIdx.x; int b = bid >> 6, k = bid & 63;
    float s = 0.f;
    for (int t = 0; t < T_; ++t) {
        const float* row = hs + (((size_t)t * B_ + b) * K_ + k) * HW;
        for (int p = threadIdx.x; p < HW; p += 256) s += row[p];
    }
    float tot = block_reduce_sum_256(s);
    if (threadIdx.x == 0) asum[bid] = tot;
}

// ---------------- VLAD: per-(b,t) outer-product GEMM ----------------
__global__ __launch_bounds__(256) void vlad_k(const float* __restrict__ assign,
    const float* __restrict__ xr, float* __restrict__ vladt)
{
    int dt = blockIdx.x, t = blockIdx.y, b = blockIdx.z;
    int q = t * B_ + b, bt = b * T_ + t, d0 = dt * 64;
    const float* ab = assign + (size_t)q * K_ * HW;
    const float* xb = xr + (size_t)bt * D_ * HW;
    __shared__ float As[16][68];
    __shared__ float Xs[16][68];
    int tx = threadIdx.x & 15, ty = threadIdx.x >> 4;
    float acc[4][4] = {{0.f}};

    for (int p0 = 0; p0 < HW; p0 += 16) {
#pragma unroll
        for (int it = 0; it < 4; ++it) {
            int e = threadIdx.x + it * 256;
            int row = e >> 4, pp = e & 15;
            As[pp][row] = ab[(size_t)row * HW + p0 + pp];
            Xs[pp][row] = xb[(size_t)(d0 + row) * HW + p0 + pp];
        }
        __syncthreads();
#pragma unroll
        for (int pp = 0; pp < 16; ++pp) {
            float4 a = *(const float4*)&As[pp][ty * 4];
            float4 xv = *(const float4*)&Xs[pp][tx * 4];
            float av[4] = {a.x, a.y, a.z, a.w};
            float xvv[4] = {xv.x, xv.y, xv.z, xv.w};
#pragma unroll
            for (int r = 0; r < 4; ++r)
#pragma unroll
                for (int s = 0; s < 4; ++s)
                    acc[r][s] = fmaf(av[r], xvv[s], acc[r][s]);
        }
        __syncthreads();
    }
#pragma unroll
    for (int r = 0; r < 4; ++r) {
        int k = ty * 4 + r;
        float4 o = {acc[r][0], acc[r][1], acc[r][2], acc[r][3]};
        *(float4*)&vladt[((size_t)bt * K_ + k) * D_ + d0 + tx * 4] = o;
    }
}

// ---------------- reduce over t, subtract a_sum*centers, intra-norm ----------------
__global__ __launch_bounds__(256) void norm1_k(const float* __restrict__ vladt,
    const float* __restrict__ asum, const float* __restrict__ centers,
    float* __restrict__ out)
{
    int bid = blockIdx.x; int b = bid >> 6, k = bid & 63; int d = threadIdx.x;
    float acc = 0.f;
#pragma unroll
    for (int t = 0; t < T_; ++t)
        acc += vladt[(((size_t)b * T_ + t) * K_ + k) * D_ + d];
    acc -= asum[bid] * centers[(size_t)k * D_ + d];
    float ss = block_reduce_sum_256(acc * acc);
    float n = fmaxf(sqrtf(ss), 1e-12f);
    out[((size_t)b * K_ + k) * D_ + d] = acc / n;
}

// ---------------- global L2 norm per b ----------------
__global__ __launch_bounds__(256) void norm2_k(float* __restrict__ out)
{
    int b = blockIdx.x;
    float* v = out + (size_t)b * (K_ * D_);
    float s = 0.f;
    for (int i = threadIdx.x; i < K_ * D_; i += 256) {
        float x = v[i];
        s = fmaf(x, x, s);
    }
    float tot = block_reduce_sum_256(s);
    float n = fmaxf(sqrtf(tot), 1e-12f);
    for (int i = threadIdx.x; i < K_ * D_; i += 256) v[i] = v[i] / n;
}

// ---------------- launch ----------------
extern "C" void kernel_launch(void* const* d_in, const int* in_sizes, int n_in,
                              void* d_out, int out_size, void* d_ws, size_t ws_size,
                              hipStream_t stream)
{
    const float* x       = (const float*)d_in[0];
    const float* redu_w  = (const float*)d_in[1];
    const float* redu_b  = (const float*)d_in[2];
    const float* share_w = (const float*)d_in[3];
    const float* share_b = (const float*)d_in[4];
    const float* Uz      = (const float*)d_in[5];
    const float* Ur      = (const float*)d_in[6];
    const float* Uh      = (const float*)d_in[7];
    const float* centers = (const float*)d_in[8];

    float* ws = (float*)d_ws;
    const size_t SZ_XR   = (size_t)128 * D_ * HW;       // 25,690,112
    const size_t SZ_WXB  = (size_t)128 * K_ * HW;       //  6,422,528
    const size_t SZ_HS   = (size_t)T_ * B_ * K_ * HW;   //  6,422,528
    const size_t SZ_PLANE= (size_t)B_ * K_ * HW;        //    401,408

    float* xr    = ws;
    float* wxb   = xr + SZ_XR;
    float* hs    = wxb + SZ_WXB;
    float* h0    = hs + SZ_HS;
    float* zbuf  = h0 + SZ_PLANE;
    float* asumb = zbuf + SZ_PLANE;          // 512 floats
    float* wsplit= asumb + 512;              // split weights region
    float* area  = wsplit + 323584;          // union: vladt | GRU split buffers

    ushort_t* whi = (ushort_t*)wsplit;            // 196608
    ushort_t* wlo = whi + 196608;
    ushort_t* shi = wlo + 196608;                 // 16384
    ushort_t* slo = shi + 16384;
    ushort_t* azh = slo + 16384;                  // 73728
    ushort_t* azl = azh + 73728;
    ushort_t* ahh = azl + 73728;                  // 36864
    ushort_t* ahl = ahh + 36864;

    float* vladt = area;                          // 2,097,152 floats
    ushort_t* hhi = (ushort_t*)area;
    ushort_t* hlo = hhi + SZ_PLANE;
    ushort_t* rhi = hlo + SZ_PLANE;
    ushort_t* rlo = rhi + SZ_PLANE;

    hipMemsetAsync(h0, 0, SZ_PLANE * sizeof(float), stream);
    hipMemsetAsync(hhi, 0, 2 * SZ_PLANE * sizeof(ushort_t), stream);

    cvt_weights<<<dim3((D_ * CIN + K_ * D_ + 128 * 576 + 64 * 576 + 255) / 256),
                  256, 0, stream>>>(redu_w, share_w, Uz, Ur, Uh,
                                    whi, wlo, shi, slo, azh, azl, ahh, ahl);

    // 1) channel reduction (split-bf16 MFMA)
    mfma_conv1x1<256, 3><<<dim3(7, 1, 128), 256, 0, stream>>>(x, whi, wlo, redu_b, xr, CIN);
    // 2) assignment logits
    mfma_conv1x1<64, 4><<<dim3(7, 1, 128), 256, 0, stream>>>(xr, shi, slo, share_b, wxb, D_);

    // 3) ConvGRU over 16 timesteps (MFMA implicit GEMM, rowchunk=1)
    for (int t = 0; t < T_; ++t) {
        const float* hp = (t == 0) ? h0 : hs + (size_t)(t - 1) * SZ_PLANE;
        gru_zr_mfma<<<dim3(28, 8, 2), 256, 0, stream>>>(hhi, hlo, azh, azl, wxb, hp,
                                                        zbuf, rhi, rlo, t);
        gru_h_mfma<<<dim3(28, 8), 256, 0, stream>>>(rhi, rlo, ahh, ahl, wxb, hp, zbuf,
                                                    hs + (size_t)t * SZ_PLANE, hhi, hlo, t);
    }

    // 4) softmax over centers, a_sum
    softmax_k<<<128, 256, 0, stream>>>(hs);
    asum_k<<<512, 256, 0, stream>>>(hs, asumb);

    // 5) VLAD aggregation + norms
    vlad_k<<<dim3(4, 16, 8), 256, 0, stream>>>(hs, xr, vladt);
    norm1_k<<<512, 256, 0, stream>>>(vladt, asumb, centers, (float*)d_out);
    norm2_k<<<8, 256, 0, stream>>>((float*)d_out);
}

// Round 5
// 674.163 us; speedup vs baseline: 7.7173x; 1.1743x over previous
//
#include <hip/hip_runtime.h>
#include <hip/hip_bf16.h>

#define T_ 16
#define B_ 8
#define CIN 768
#define D_ 256
#define K_ 64
#define HW 784
#define W_ 28

typedef short short8 __attribute__((ext_vector_type(8)));
typedef short short4v __attribute__((ext_vector_type(4)));
typedef float floatx4 __attribute__((ext_vector_type(4)));
typedef unsigned short ushort_t;

// ---------------- bf16 split helpers ----------------
__device__ __forceinline__ unsigned short f2bf(float x) {
    union { float f; unsigned u; } v; v.f = x;
    unsigned u = v.u;
    unsigned r = (u + 0x7fffu + ((u >> 16) & 1u)) >> 16;   // RNE
    return (unsigned short)r;
}
__device__ __forceinline__ float bf2f(unsigned short h) {
    union { unsigned u; float f; } v; v.u = ((unsigned)h) << 16; return v.f;
}

// ---------------- block reduce helper ----------------
__device__ __forceinline__ float block_reduce_sum_256(float v) {
    for (int off = 32; off > 0; off >>= 1) v += __shfl_down(v, off, 64);
    __shared__ float red[4];
    __shared__ float tot;
    int lane = threadIdx.x & 63, wid = threadIdx.x >> 6;
    if (lane == 0) red[wid] = v;
    __syncthreads();
    if (threadIdx.x == 0) tot = red[0] + red[1] + red[2] + red[3];
    __syncthreads();
    return tot;
}

// ---------------- weight split (once per launch) ----------------
__global__ __launch_bounds__(256) void cvt_weights(
    const float* __restrict__ rw, const float* __restrict__ sw,
    const float* __restrict__ Uz, const float* __restrict__ Ur,
    const float* __restrict__ Uh,
    ushort_t* __restrict__ whi, ushort_t* __restrict__ wlo,
    ushort_t* __restrict__ shi, ushort_t* __restrict__ slo,
    ushort_t* __restrict__ azh, ushort_t* __restrict__ azl,
    ushort_t* __restrict__ ahh, ushort_t* __restrict__ ahl)
{
    int i = blockIdx.x * 256 + threadIdx.x;
    const int nR = D_ * CIN;           // 196608
    const int nS = K_ * D_;            // 16384
    const int nZR = 128 * 576;         // 73728
    const int nH = 64 * 576;           // 36864
    if (i < nR) {
        float x = rw[i];
        unsigned short h = f2bf(x);
        whi[i] = h; wlo[i] = f2bf(x - bf2f(h));
    } else if (i < nR + nS) {
        int j = i - nR;
        float x = sw[j];
        unsigned short h = f2bf(x);
        shi[j] = h; slo[j] = f2bf(x - bf2f(h));
    } else if (i < nR + nS + nZR) {
        int j = i - nR - nS;
        int row = j / 576, kk = j - row * 576;
        int tap = kk >> 6, c = kk & 63;
        const float* U = (row < 64) ? Uz : Ur;
        float x = U[(((size_t)(row & 63)) * 64 + c) * 9 + tap];
        unsigned short h = f2bf(x);
        azh[j] = h; azl[j] = f2bf(x - bf2f(h));
    } else if (i < nR + nS + nZR + nH) {
        int j = i - nR - nS - nZR;
        int row = j / 576, kk = j - row * 576;
        int tap = kk >> 6, c = kk & 63;
        float x = Uh[(((size_t)row) * 64 + c) * 9 + tap];
        unsigned short h = f2bf(x);
        ahh[j] = h; ahl[j] = f2bf(x - bf2f(h));
    }
}

// ---------------- 1x1 conv as split-bf16 MFMA GEMM (v3: T14 pipeline) ----------------
// B reg-double-buffered (issue loads for k+1 before MFMA of k, write after barrier);
// A-frag L2 loads issued early each step. LDS: B only (17.9 KB).
template<int BM, int KD>
__global__ __launch_bounds__(256, 2) void mfma_conv1x1(
    const float* __restrict__ X, const ushort_t* __restrict__ Whi,
    const ushort_t* __restrict__ Wlo, const float* __restrict__ bias,
    float* __restrict__ Out)
{
    const int nt = blockIdx.x, bt = blockIdx.z;
    const int p0 = nt * 112;
    const int tid = threadIdx.x, lane = tid & 63, wv = tid >> 6;
    const float* Xb = X + (size_t)bt * KD * HW;
    float* Ob = Out + (size_t)bt * BM * HW;

    __shared__ ushort_t lB[2][112 * 40];   // [hi/lo][pp][k 0..31], rows padded to 40

    constexpr int NI = (BM == 256) ? 7 : 2;
    constexpr int NKS = KD / 32;           // 24 or 8 (even)
    floatx4 acc[4][NI];
#pragma unroll
    for (int a = 0; a < 4; ++a)
#pragma unroll
        for (int b = 0; b < NI; ++b) acc[a][b] = (floatx4){0.f, 0.f, 0.f, 0.f};

    const int koff = (lane >> 4) * 8;
    const int li = lane & 15;
    const int mbase = (BM == 256) ? wv * 64 : 0;

    // B staging units: u0 = tid, u1 = tid+256 (valid if tid<192)
    const int u0j = tid / 112, u0p = tid - u0j * 112;
    const bool u1v = tid < 192;
    const int u1j = (tid + 256) / 112, u1p = (tid + 256) - u1j * 112;

    float b0[16], b1[16];
    short8 ahi[4], alo[4];

    auto loadB = [&](int k0, float* bb) {
        const float* xp0 = Xb + (size_t)(k0 + u0j * 8) * HW + p0 + u0p;
#pragma unroll
        for (int c = 0; c < 8; ++c) bb[c] = xp0[c * HW];
        if (u1v) {
            const float* xp1 = Xb + (size_t)(k0 + u1j * 8) * HW + p0 + u1p;
#pragma unroll
            for (int c = 0; c < 8; ++c) bb[8 + c] = xp1[c * HW];
        }
    };
    auto writeB = [&](const float* bb) {
        short8 vh, vl;
#pragma unroll
        for (int c = 0; c < 8; ++c) {
            unsigned short h = f2bf(bb[c]);
            vh[c] = (short)h; vl[c] = (short)f2bf(bb[c] - bf2f(h));
        }
        *(short8*)&lB[0][u0p * 40 + u0j * 8] = vh;
        *(short8*)&lB[1][u0p * 40 + u0j * 8] = vl;
        if (u1v) {
#pragma unroll
            for (int c = 0; c < 8; ++c) {
                unsigned short h = f2bf(bb[8 + c]);
                vh[c] = (short)h; vl[c] = (short)f2bf(bb[8 + c] - bf2f(h));
            }
            *(short8*)&lB[0][u1p * 40 + u1j * 8] = vh;
            *(short8*)&lB[1][u1p * 40 + u1j * 8] = vl;
        }
    };
    auto loadA = [&](int k0) {
#pragma unroll
        for (int mi = 0; mi < 4; ++mi) {
            int m = mbase + mi * 16 + li;
            ahi[mi] = *(const short8*)(Whi + (size_t)m * KD + k0 + koff);
            alo[mi] = *(const short8*)(Wlo + (size_t)m * KD + k0 + koff);
        }
    };
    auto domfma = [&]() {
        if constexpr (BM == 256) {
#pragma unroll
            for (int ni = 0; ni < 7; ++ni) {
                int n = ni * 16 + li;
                short8 bhi = *(const short8*)&lB[0][n * 40 + koff];
                short8 blo = *(const short8*)&lB[1][n * 40 + koff];
#pragma unroll
                for (int mi = 0; mi < 4; ++mi) {
                    acc[mi][ni] = __builtin_amdgcn_mfma_f32_16x16x32_bf16(ahi[mi], bhi, acc[mi][ni], 0, 0, 0);
                    acc[mi][ni] = __builtin_amdgcn_mfma_f32_16x16x32_bf16(ahi[mi], blo, acc[mi][ni], 0, 0, 0);
                    acc[mi][ni] = __builtin_amdgcn_mfma_f32_16x16x32_bf16(alo[mi], bhi, acc[mi][ni], 0, 0, 0);
                }
            }
        } else {
#pragma unroll
            for (int nj = 0; nj < 2; ++nj) {
                int ni = wv * 2 + nj;
                if (ni >= 7) break;
                int n = ni * 16 + li;
                short8 bhi = *(const short8*)&lB[0][n * 40 + koff];
                short8 blo = *(const short8*)&lB[1][n * 40 + koff];
#pragma unroll
                for (int mi = 0; mi < 4; ++mi) {
                    acc[mi][nj] = __builtin_amdgcn_mfma_f32_16x16x32_bf16(ahi[mi], bhi, acc[mi][nj], 0, 0, 0);
                    acc[mi][nj] = __builtin_amdgcn_mfma_f32_16x16x32_bf16(ahi[mi], blo, acc[mi][nj], 0, 0, 0);
                    acc[mi][nj] = __builtin_amdgcn_mfma_f32_16x16x32_bf16(alo[mi], bhi, acc[mi][nj], 0, 0, 0);
                }
            }
        }
    };

    loadB(0, b0);
    for (int ks = 0; ks < NKS; ks += 2) {
        // even half
        loadA(ks * 32);                        // issue early (hidden by writeB+barrier)
        writeB(b0);
        __syncthreads();
        if (ks + 1 < NKS) loadB((ks + 1) * 32, b1);
        domfma();
        __syncthreads();
        // odd half (NKS even, guards uniform)
        loadA((ks + 1) * 32);
        writeB(b1);
        __syncthreads();
        if (ks + 2 < NKS) loadB((ks + 2) * 32, b0);
        domfma();
        __syncthreads();
    }

    if constexpr (BM == 256) {
#pragma unroll
        for (int mi = 0; mi < 4; ++mi) {
            int m0g = wv * 64 + mi * 16 + ((lane >> 4) << 2);
#pragma unroll
            for (int ni = 0; ni < 7; ++ni) {
                int p = p0 + ni * 16 + li;
#pragma unroll
                for (int r = 0; r < 4; ++r)
                    Ob[(size_t)(m0g + r) * HW + p] = acc[mi][ni][r] + bias[m0g + r];
            }
        }
    } else {
#pragma unroll
        for (int nj = 0; nj < 2; ++nj) {
            int ni = wv * 2 + nj;
            if (ni >= 7) break;
            int p = p0 + ni * 16 + li;
#pragma unroll
            for (int mi = 0; mi < 4; ++mi) {
                int m0g = mi * 16 + ((lane >> 4) << 2);
#pragma unroll
                for (int r = 0; r < 4; ++r)
                    Ob[(size_t)(m0g + r) * HW + p] = acc[mi][nj][r] + bias[m0g + r];
            }
        }
    }
}

// ---------------- fused GRU step: one dispatch per timestep ----------------
// Block = (y-row, b), 512 threads / 8 waves. Waves 0-3: z (kept in LDS);
// waves 4-7: r for rows y-1..y+1 (redundant halo compute), r*h -> LDS;
// barrier; waves 0-3: candidate conv + state update. State split-bf16 NHWC,
// double-buffered across steps (read hR*, write hW*).
__global__ __launch_bounds__(512, 2) void gru_step(
    const ushort_t* __restrict__ hRhi, const ushort_t* __restrict__ hRlo,
    ushort_t* __restrict__ hWhi, ushort_t* __restrict__ hWlo,
    const ushort_t* __restrict__ azh, const ushort_t* __restrict__ azl,
    const ushort_t* __restrict__ ahh, const ushort_t* __restrict__ ahl,
    const float* __restrict__ wxb, float* __restrict__ hs_t, int t)
{
    const int y0 = blockIdx.x, b = blockIdx.y;
    const int tid = threadIdx.x, lane = tid & 63, wv = tid >> 6;
    const int li = lane & 15, koff8 = (lane >> 4) * 8, kq = (lane >> 4) * 4;

    __shared__ ushort_t Hhi[5 * 30 * 72], Hlo[5 * 30 * 72];  // h tile rows y0-2..y0+2
    __shared__ ushort_t Rhi[3 * 30 * 72], Rlo[3 * 30 * 72];  // r*h rows y0-1..y0+1
    __shared__ float zs[28 * 68];                            // z[col][k], padded

    // stage H (5-row halo) + zero-fill R
    {
        const ushort_t* gh = hRhi + (size_t)b * HW * 64;
        const ushort_t* gl = hRlo + (size_t)b * HW * 64;
        for (int e = tid; e < 1200; e += 512) {
            int r = e / 240, rem = e - r * 240;
            int lx = rem >> 3, j = rem & 7;
            int gy = y0 - 2 + r, gx = lx - 1;
            short8 vh = {0,0,0,0,0,0,0,0}, vl = {0,0,0,0,0,0,0,0};
            if (gy >= 0 && gy < 28 && gx >= 0 && gx < 28) {
                size_t go = ((size_t)(gy * 28 + gx)) * 64 + j * 8;
                vh = *(const short8*)(gh + go);
                vl = *(const short8*)(gl + go);
            }
            int lo = (r * 30 + lx) * 72 + j * 8;
            *(short8*)&Hhi[lo] = vh;
            *(short8*)&Hlo[lo] = vl;
        }
        short8 z8 = {0,0,0,0,0,0,0,0};
        for (int e = tid; e < 1620; e += 512) {
            if (e < 810) *(short8*)&Rhi[e * 8] = z8;
            else         *(short8*)&Rlo[(e - 810) * 8] = z8;
        }
    }
    __syncthreads();

    const float* wx = wxb + ((size_t)(b * T_ + t) * K_) * HW;
    const int c0 = li;
    const int c1 = (li < 12) ? 16 + li : 0;   // clamp invalid cols

    if (wv < 4) {
        // ---- z gate (output row y0, k rows kb..kb+15)
        const int kb = wv * 16;
        const ushort_t* Ah = azh + (size_t)(kb + li) * 576;
        const ushort_t* Al = azl + (size_t)(kb + li) * 576;
        floatx4 az[2];
        az[0] = (floatx4){0.f,0.f,0.f,0.f}; az[1] = (floatx4){0.f,0.f,0.f,0.f};
#pragma unroll
        for (int tap = 0; tap < 9; ++tap) {
            const int dy = tap / 3, dx = tap - dy * 3;
#pragma unroll
            for (int ch = 0; ch < 2; ++ch) {
                short8 whi_ = *(const short8*)(Ah + tap * 64 + ch * 32 + koff8);
                short8 wlo_ = *(const short8*)(Al + tap * 64 + ch * 32 + koff8);
                int cb = ch * 32 + koff8;
                int o0 = ((dy + 1) * 30 + c0 + dx) * 72 + cb;
                int o1 = ((dy + 1) * 30 + c1 + dx) * 72 + cb;
                short8 bh0 = *(const short8*)&Hhi[o0];
                short8 bl0 = *(const short8*)&Hlo[o0];
                short8 bh1 = *(const short8*)&Hhi[o1];
                short8 bl1 = *(const short8*)&Hlo[o1];
                az[0] = __builtin_amdgcn_mfma_f32_16x16x32_bf16(whi_, bh0, az[0], 0, 0, 0);
                az[0] = __builtin_amdgcn_mfma_f32_16x16x32_bf16(whi_, bl0, az[0], 0, 0, 0);
                az[0] = __builtin_amdgcn_mfma_f32_16x16x32_bf16(wlo_, bh0, az[0], 0, 0, 0);
                az[1] = __builtin_amdgcn_mfma_f32_16x16x32_bf16(whi_, bh1, az[1], 0, 0, 0);
                az[1] = __builtin_amdgcn_mfma_f32_16x16x32_bf16(whi_, bl1, az[1], 0, 0, 0);
                az[1] = __builtin_amdgcn_mfma_f32_16x16x32_bf16(wlo_, bh1, az[1], 0, 0, 0);
            }
        }
        const int kb4 = kb + kq;
#pragma unroll
        for (int cf = 0; cf < 2; ++cf) {
            int c = cf * 16 + li;
            if (c < 28) {
                floatx4 zv;
#pragma unroll
                for (int r = 0; r < 4; ++r)
                    zv[r] = 1.f / (1.f + __expf(-(wx[(size_t)(kb4 + r) * HW + y0 * 28 + c] + az[cf][r])));
                *(floatx4*)&zs[c * 68 + kb4] = zv;
            }
        }
    } else {
        // ---- r gate for rows y0-1..y0+1 (halo-redundant), r*h -> R tile
        const int kb = (wv - 4) * 16;
        const ushort_t* Ah = azh + (size_t)(64 + kb + li) * 576;
        const ushort_t* Al = azl + (size_t)(64 + kb + li) * 576;
        floatx4 ar[3][2];
#pragma unroll
        for (int i = 0; i < 3; ++i) {
            ar[i][0] = (floatx4){0.f,0.f,0.f,0.f};
            ar[i][1] = (floatx4){0.f,0.f,0.f,0.f};
        }
#pragma unroll
        for (int tap = 0; tap < 9; ++tap) {
            const int dy = tap / 3, dx = tap - dy * 3;
#pragma unroll
            for (int ch = 0; ch < 2; ++ch) {
                short8 whi_ = *(const short8*)(Ah + tap * 64 + ch * 32 + koff8);
                short8 wlo_ = *(const short8*)(Al + tap * 64 + ch * 32 + koff8);
                int cb = ch * 32 + koff8;
#pragma unroll
                for (int rr = 0; rr < 3; ++rr) {
                    int o0 = ((rr + dy) * 30 + c0 + dx) * 72 + cb;
                    int o1 = ((rr + dy) * 30 + c1 + dx) * 72 + cb;
                    short8 bh0 = *(const short8*)&Hhi[o0];
                    short8 bl0 = *(const short8*)&Hlo[o0];
                    short8 bh1 = *(const short8*)&Hhi[o1];
                    short8 bl1 = *(const short8*)&Hlo[o1];
                    ar[rr][0] = __builtin_amdgcn_mfma_f32_16x16x32_bf16(whi_, bh0, ar[rr][0], 0, 0, 0);
                    ar[rr][0] = __builtin_amdgcn_mfma_f32_16x16x32_bf16(whi_, bl0, ar[rr][0], 0, 0, 0);
                    ar[rr][0] = __builtin_amdgcn_mfma_f32_16x16x32_bf16(wlo_, bh0, ar[rr][0], 0, 0, 0);
                    ar[rr][1] = __builtin_amdgcn_mfma_f32_16x16x32_bf16(whi_, bh1, ar[rr][1], 0, 0, 0);
                    ar[rr][1] = __builtin_amdgcn_mfma_f32_16x16x32_bf16(whi_, bl1, ar[rr][1], 0, 0, 0);
                    ar[rr][1] = __builtin_amdgcn_mfma_f32_16x16x32_bf16(wlo_, bh1, ar[rr][1], 0, 0, 0);
                }
            }
        }
        const int kb4 = kb + kq;
#pragma unroll
        for (int rr = 0; rr < 3; ++rr) {
            int gy = y0 - 1 + rr;
            if (gy < 0 || gy >= 28) continue;
#pragma unroll
            for (int cf = 0; cf < 2; ++cf) {
                int c = cf * 16 + li;
                if (c >= 28) continue;
                short4v ph = *(const short4v*)&Hhi[((rr + 1) * 30 + c + 1) * 72 + kb4];
                short4v pl = *(const short4v*)&Hlo[((rr + 1) * 30 + c + 1) * 72 + kb4];
                short4v vh, vl;
#pragma unroll
                for (int r = 0; r < 4; ++r) {
                    float rv = 1.f / (1.f + __expf(-(wx[(size_t)(kb4 + r) * HW + gy * 28 + c] + ar[rr][cf][r])));
                    float hv = bf2f((unsigned short)ph[r]) + bf2f((unsigned short)pl[r]);
                    float rh = rv * hv;
                    unsigned short h = f2bf(rh);
                    vh[r] = (short)h; vl[r] = (short)f2bf(rh - bf2f(h));
                }
                *(short4v*)&Rhi[(rr * 30 + c + 1) * 72 + kb4] = vh;
                *(short4v*)&Rlo[(rr * 30 + c + 1) * 72 + kb4] = vl;
            }
        }
    }
    __syncthreads();

    if (wv < 4) {
        // ---- candidate conv + state update (output row y0)
        const int kb = wv * 16;
        const ushort_t* Ah = ahh + (size_t)(kb + li) * 576;
        const ushort_t* Al = ahl + (size_t)(kb + li) * 576;
        floatx4 ac[2];
        ac[0] = (floatx4){0.f,0.f,0.f,0.f}; ac[1] = (floatx4){0.f,0.f,0.f,0.f};
#pragma unroll
        for (int tap = 0; tap < 9; ++tap) {
            const int dy = tap / 3, dx = tap - dy * 3;
#pragma unroll
            for (int ch = 0; ch < 2; ++ch) {
                short8 whi_ = *(const short8*)(Ah + tap * 64 + ch * 32 + koff8);
                short8 wlo_ = *(const short8*)(Al + tap * 64 + ch * 32 + koff8);
                int cb = ch * 32 + koff8;
                int o0 = (dy * 30 + c0 + dx) * 72 + cb;
                int o1 = (dy * 30 + c1 + dx) * 72 + cb;
                short8 bh0 = *(const short8*)&Rhi[o0];
                short8 bl0 = *(const short8*)&Rlo[o0];
                short8 bh1 = *(const short8*)&Rhi[o1];
                short8 bl1 = *(const short8*)&Rlo[o1];
                ac[0] = __builtin_amdgcn_mfma_f32_16x16x32_bf16(whi_, bh0, ac[0], 0, 0, 0);
                ac[0] = __builtin_amdgcn_mfma_f32_16x16x32_bf16(whi_, bl0, ac[0], 0, 0, 0);
                ac[0] = __builtin_amdgcn_mfma_f32_16x16x32_bf16(wlo_, bh0, ac[0], 0, 0, 0);
                ac[1] = __builtin_amdgcn_mfma_f32_16x16x32_bf16(whi_, bh1, ac[1], 0, 0, 0);
                ac[1] = __builtin_amdgcn_mfma_f32_16x16x32_bf16(whi_, bl1, ac[1], 0, 0, 0);
                ac[1] = __builtin_amdgcn_mfma_f32_16x16x32_bf16(wlo_, bh1, ac[1], 0, 0, 0);
            }
        }
        const int kb4 = kb + kq;
        float* hsb = hs_t + (size_t)b * K_ * HW;
#pragma unroll
        for (int cf = 0; cf < 2; ++cf) {
            int c = cf * 16 + li;
            if (c >= 28) continue;
            int p = y0 * 28 + c;
            floatx4 zv = *(const floatx4*)&zs[c * 68 + kb4];
            short4v ph = *(const short4v*)&Hhi[(2 * 30 + c + 1) * 72 + kb4];
            short4v pl = *(const short4v*)&Hlo[(2 * 30 + c + 1) * 72 + kb4];
            short4v vh, vl;
#pragma unroll
            for (int r = 0; r < 4; ++r) {
                int k = kb4 + r;
                float xv = wx[(size_t)k * HW + p] + ac[cf][r];
                float e2 = __expf(2.f * xv);
                float th = 1.f - 2.f / (e2 + 1.f);
                float hp = bf2f((unsigned short)ph[r]) + bf2f((unsigned short)pl[r]);
                float hn = (1.f - zv[r]) * th + zv[r] * hp;
                hsb[(size_t)k * HW + p] = hn;
                unsigned short h = f2bf(hn);
                vh[r] = (short)h; vl[r] = (short)f2bf(hn - bf2f(h));
            }
            size_t o = ((size_t)(b * HW) + p) * 64 + kb4;
            *(short4v*)(hWhi + o) = vh;
            *(short4v*)(hWlo + o) = vl;
        }
    }
}

// ---------------- softmax over k (in place on hs) ----------------
__global__ __launch_bounds__(256) void softmax_k(float* __restrict__ hs)
{
    int q = blockIdx.x;
    int py = blockIdx.y;
    float* base = hs + (size_t)q * K_ * HW;
    for (int p = py * 392 + threadIdx.x; p < (py + 1) * 392 && p < HW; p += 256) {
        float v[64];
        float m = -1e30f;
#pragma unroll
        for (int k = 0; k < 64; ++k) {
            v[k] = base[(size_t)k * HW + p];
            m = fmaxf(m, v[k]);
        }
        float s = 0.f;
#pragma unroll
        for (int k = 0; k < 64; ++k) {
            v[k] = __expf(v[k] - m);
            s += v[k];
        }
        float inv = 1.f / s;
#pragma unroll
        for (int k = 0; k < 64; ++k)
            base[(size_t)k * HW + p] = v[k] * inv;
    }
}

// ---------------- a_sum ----------------
__global__ __launch_bounds__(256) void asum_k(const float* __restrict__ hs,
                                              float* __restrict__ asum)
{
    int bid = blockIdx.x; int b = bid >> 6, k = bid & 63;
    float s = 0.f;
    for (int t = 0; t < T_; ++t) {
        const float* row = hs + (((size_t)t * B_ + b) * K_ + k) * HW;
        for (int p = threadIdx.x; p < HW; p += 256) s += row[p];
    }
    float tot = block_reduce_sum_256(s);
    if (threadIdx.x == 0) asum[bid] = tot;
}

// ---------------- VLAD: per-(b,t) outer-product GEMM ----------------
__global__ __launch_bounds__(256) void vlad_k(const float* __restrict__ assign,
    const float* __restrict__ xr, float* __restrict__ vladt)
{
    int dt = blockIdx.x, t = blockIdx.y, b = blockIdx.z;
    int q = t * B_ + b, bt = b * T_ + t, d0 = dt * 64;
    const float* ab = assign + (size_t)q * K_ * HW;
    const float* xb = xr + (size_t)bt * D_ * HW;
    __shared__ float As[16][68];
    __shared__ float Xs[16][68];
    int tx = threadIdx.x & 15, ty = threadIdx.x >> 4;
    float acc[4][4] = {{0.f}};

    for (int p0 = 0; p0 < HW; p0 += 16) {
#pragma unroll
        for (int it = 0; it < 4; ++it) {
            int e = threadIdx.x + it * 256;
            int row = e >> 4, pp = e & 15;
            As[pp][row] = ab[(size_t)row * HW + p0 + pp];
            Xs[pp][row] = xb[(size_t)(d0 + row) * HW + p0 + pp];
        }
        __syncthreads();
#pragma unroll
        for (int pp = 0; pp < 16; ++pp) {
            float4 a = *(const float4*)&As[pp][ty * 4];
            float4 xv = *(const float4*)&Xs[pp][tx * 4];
            float av[4] = {a.x, a.y, a.z, a.w};
            float xvv[4] = {xv.x, xv.y, xv.z, xv.w};
#pragma unroll
            for (int r = 0; r < 4; ++r)
#pragma unroll
                for (int s = 0; s < 4; ++s)
                    acc[r][s] = fmaf(av[r], xvv[s], acc[r][s]);
        }
        __syncthreads();
    }
#pragma unroll
    for (int r = 0; r < 4; ++r) {
        int k = ty * 4 + r;
        float4 o = {acc[r][0], acc[r][1], acc[r][2], acc[r][3]};
        *(float4*)&vladt[((size_t)bt * K_ + k) * D_ + d0 + tx * 4] = o;
    }
}

// ---------------- reduce over t, subtract a_sum*centers, intra-norm ----------------
__global__ __launch_bounds__(256) void norm1_k(const float* __restrict__ vladt,
    const float* __restrict__ asum, const float* __restrict__ centers,
    float* __restrict__ out)
{
    int bid = blockIdx.x; int b = bid >> 6, k = bid & 63; int d = threadIdx.x;
    float acc = 0.f;
#pragma unroll
    for (int t = 0; t < T_; ++t)
        acc += vladt[(((size_t)b * T_ + t) * K_ + k) * D_ + d];
    acc -= asum[bid] * centers[(size_t)k * D_ + d];
    float ss = block_reduce_sum_256(acc * acc);
    float n = fmaxf(sqrtf(ss), 1e-12f);
    out[((size_t)b * K_ + k) * D_ + d] = acc / n;
}

// ---------------- global L2 norm per b ----------------
__global__ __launch_bounds__(256) void norm2_k(float* __restrict__ out)
{
    int b = blockIdx.x;
    float* v = out + (size_t)b * (K_ * D_);
    float s = 0.f;
    for (int i = threadIdx.x; i < K_ * D_; i += 256) {
        float x = v[i];
        s = fmaf(x, x, s);
    }
    float tot = block_reduce_sum_256(s);
    float n = fmaxf(sqrtf(tot), 1e-12f);
    for (int i = threadIdx.x; i < K_ * D_; i += 256) v[i] = v[i] / n;
}

// ---------------- launch ----------------
extern "C" void kernel_launch(void* const* d_in, const int* in_sizes, int n_in,
                              void* d_out, int out_size, void* d_ws, size_t ws_size,
                              hipStream_t stream)
{
    const float* x       = (const float*)d_in[0];
    const float* redu_w  = (const float*)d_in[1];
    const float* redu_b  = (const float*)d_in[2];
    const float* share_w = (const float*)d_in[3];
    const float* share_b = (const float*)d_in[4];
    const float* Uz      = (const float*)d_in[5];
    const float* Ur      = (const float*)d_in[6];
    const float* Uh      = (const float*)d_in[7];
    const float* centers = (const float*)d_in[8];

    float* ws = (float*)d_ws;
    const size_t SZ_XR   = (size_t)128 * D_ * HW;       // 25,690,112
    const size_t SZ_WXB  = (size_t)128 * K_ * HW;       //  6,422,528
    const size_t SZ_HS   = (size_t)T_ * B_ * K_ * HW;   //  6,422,528
    const size_t SZ_PLANE= (size_t)B_ * K_ * HW;        //    401,408

    float* xr    = ws;
    float* wxb   = xr + SZ_XR;
    float* hs    = wxb + SZ_WXB;
    float* asumb = hs + SZ_HS;               // 512 floats
    float* wsplit= asumb + 512;              // split weights (323,584 floats)
    float* area  = wsplit + 323584;          // union: vladt | GRU split state

    ushort_t* whi = (ushort_t*)wsplit;            // 196608
    ushort_t* wlo = whi + 196608;
    ushort_t* shi = wlo + 196608;                 // 16384
    ushort_t* slo = shi + 16384;
    ushort_t* azh = slo + 16384;                  // 73728
    ushort_t* azl = azh + 73728;
    ushort_t* ahh = azl + 73728;                  // 36864
    ushort_t* ahl = ahh + 36864;

    float* vladt = area;                          // 2,097,152 floats (after GRU)
    ushort_t* st = (ushort_t*)area;               // GRU double-buffered state
    ushort_t* h0hi = st;
    ushort_t* h0lo = st + SZ_PLANE;
    ushort_t* h1hi = st + 2 * SZ_PLANE;
    ushort_t* h1lo = st + 3 * SZ_PLANE;

    hipMemsetAsync(h0hi, 0, 2 * SZ_PLANE * sizeof(ushort_t), stream);  // h0hi+h0lo

    cvt_weights<<<dim3((D_ * CIN + K_ * D_ + 128 * 576 + 64 * 576 + 255) / 256),
                  256, 0, stream>>>(redu_w, share_w, Uz, Ur, Uh,
                                    whi, wlo, shi, slo, azh, azl, ahh, ahl);

    // 1) channel reduction (split-bf16 MFMA, pipelined)
    mfma_conv1x1<256, CIN><<<dim3(7, 1, 128), 256, 0, stream>>>(x, whi, wlo, redu_b, xr);
    // 2) assignment logits
    mfma_conv1x1<64, D_><<<dim3(7, 1, 128), 256, 0, stream>>>(xr, shi, slo, share_b, wxb);

    // 3) ConvGRU: one fused dispatch per timestep
    for (int t = 0; t < T_; ++t) {
        const ushort_t* rh_ = (t & 1) ? h1hi : h0hi;
        const ushort_t* rl_ = (t & 1) ? h1lo : h0lo;
        ushort_t* wh_ = (t & 1) ? h0hi : h1hi;
        ushort_t* wl_ = (t & 1) ? h0lo : h1lo;
        gru_step<<<dim3(28, 8), 512, 0, stream>>>(rh_, rl_, wh_, wl_,
                                                  azh, azl, ahh, ahl,
                                                  wxb, hs + (size_t)t * SZ_PLANE, t);
    }

    // 4) softmax over centers, a_sum
    softmax_k<<<dim3(128, 2), 256, 0, stream>>>(hs);
    asum_k<<<512, 256, 0, stream>>>(hs, asumb);

    // 5) VLAD aggregation + norms
    vlad_k<<<dim3(4, 16, 8), 256, 0, stream>>>(hs, xr, vladt);
    norm1_k<<<512, 256, 0, stream>>>(vladt, asumb, centers, (float*)d_out);
    norm2_k<<<8, 256, 0, stream>>>((float*)d_out);
}